// Round 2
// baseline (629.280 us; speedup 1.0000x reference)
//
#include <hip/hip_runtime.h>
#include <hip/hip_bf16.h>
#include <math.h>

#define D 128

typedef __attribute__((ext_vector_type(8))) short short8;
typedef __attribute__((ext_vector_type(4))) float f32x4;

__device__ __forceinline__ float bf2f(unsigned short u) {
    union { unsigned int i; float f; } x; x.i = ((unsigned int)u) << 16; return x.f;
}
__device__ __forceinline__ unsigned short f2bf(float f) {
    unsigned int i = __float_as_uint(f);
    unsigned int r = (i + 0x7FFFu + ((i >> 16) & 1u)) >> 16;  // RNE
    return (unsigned short)r;
}

// ---------------- dtype detect: fp32 inputs read as shorts have random exponent fields ----------------
__global__ void k_detect(const unsigned short* __restrict__ x, int* __restrict__ flag) {
    __shared__ int bad;
    if (threadIdx.x == 0) bad = 0;
    __syncthreads();
    unsigned int e = (x[threadIdx.x] >> 7) & 0xFFu;
    if (e < 100u || e > 140u) atomicAdd(&bad, 1);
    __syncthreads();
    if (threadIdx.x == 0) *flag = (bad > 48) ? 1 : 0;
}

// normalize one tensor to bf16 (convert from f32 if flag, else copy bf16)
__global__ void k_norm(const void* __restrict__ in, unsigned short* __restrict__ out,
                       int n, const int* __restrict__ flag) {
    int i = blockIdx.x * blockDim.x + threadIdx.x;
    if (i >= n) return;
    if (*flag) out[i] = f2bf(((const float*)in)[i]);
    else       out[i] = ((const unsigned short*)in)[i];
}

// ---------------- GEMM: C[M,ldc] (+coloff) = A[M,128] @ W[128,128] + bias ----------------
__global__ __launch_bounds__(256) void gemm128(
    const unsigned short* __restrict__ A,
    const unsigned short* __restrict__ W,
    const unsigned short* __restrict__ bias,
    unsigned short* __restrict__ C,
    int M, int ldc, int coloff)
{
    __shared__ unsigned short As[128 * 128];
    __shared__ unsigned short Wt[128 * 128];  // Wt[n][k]

    int t = threadIdx.x;
    int blockRow = blockIdx.x * 128;

    #pragma unroll
    for (int i = 0; i < 8; ++i) {
        int ch = t + i * 256;          // 0..2047
        int row = ch >> 4;
        int kc  = ch & 15;
        int grow = blockRow + row;
        uint4 v = make_uint4(0u, 0u, 0u, 0u);
        if (grow < M) v = *((const uint4*)(A + (size_t)grow * D + kc * 8));
        int kcs = kc ^ (row & 15);
        *((uint4*)&As[row * 128 + kcs * 8]) = v;
    }
    #pragma unroll
    for (int i = 0; i < 8; ++i) {
        int ch = t + i * 256;
        int k  = ch >> 4;
        int n0 = (ch & 15) * 8;
        uint4 v = *((const uint4*)(W + k * D + n0));
        const unsigned short* pv = (const unsigned short*)&v;
        int kc = k >> 3;
        int ko = k & 7;
        #pragma unroll
        for (int j = 0; j < 8; ++j) {
            int n = n0 + j;
            Wt[n * 128 + (kc ^ (n & 15)) * 8 + ko] = pv[j];
        }
    }
    __syncthreads();

    int wave = t >> 6;
    int lane = t & 63;
    int quad = lane >> 4;
    int l16  = lane & 15;
    int rowbase = wave * 32;

    f32x4 acc[2][8];
    #pragma unroll
    for (int a = 0; a < 2; ++a)
        #pragma unroll
        for (int b = 0; b < 8; ++b) acc[a][b] = (f32x4){0.f, 0.f, 0.f, 0.f};

    #pragma unroll
    for (int ks = 0; ks < 4; ++ks) {
        int chunk = ks * 4 + quad;
        short8 af[2];
        short8 bf[8];
        #pragma unroll
        for (int rt = 0; rt < 2; ++rt) {
            int r = rowbase + rt * 16 + l16;
            af[rt] = *((const short8*)&As[r * 128 + (chunk ^ (r & 15)) * 8]);
        }
        #pragma unroll
        for (int ct = 0; ct < 8; ++ct) {
            int n = ct * 16 + l16;
            bf[ct] = *((const short8*)&Wt[n * 128 + (chunk ^ (n & 15)) * 8]);
        }
        #pragma unroll
        for (int rt = 0; rt < 2; ++rt)
            #pragma unroll
            for (int ct = 0; ct < 8; ++ct)
                acc[rt][ct] = __builtin_amdgcn_mfma_f32_16x16x32_bf16(af[rt], bf[ct], acc[rt][ct], 0, 0, 0);
    }

    #pragma unroll
    for (int rt = 0; rt < 2; ++rt) {
        #pragma unroll
        for (int ct = 0; ct < 8; ++ct) {
            int col = ct * 16 + l16;
            float bv = bias ? bf2f(bias[col]) : 0.f;
            #pragma unroll
            for (int r = 0; r < 4; ++r) {
                int grow = blockRow + rowbase + rt * 16 + quad * 4 + r;
                if (grow < M) {
                    float v = acc[rt][ct][r] + bv;
                    C[(size_t)grow * ldc + coloff + col] = f2bf(v);
                }
            }
        }
    }
}

// ---------------- CSR build ----------------
__global__ void k_count(const int* __restrict__ ei, int E,
                        unsigned int* __restrict__ cnt_dst, unsigned int* __restrict__ deg_src) {
    int e = blockIdx.x * blockDim.x + threadIdx.x;
    if (e < E) {
        atomicAdd(&cnt_dst[ei[e]], 1u);
        atomicAdd(&deg_src[ei[E + e]], 1u);
    }
}

__global__ void k_scan1(const unsigned int* __restrict__ cnt, unsigned int* __restrict__ excl,
                        unsigned int* __restrict__ bsum, int N) {
    __shared__ unsigned int sm[256];
    int t = threadIdx.x;
    int i = blockIdx.x * 256 + t;
    unsigned int v = (i < N) ? cnt[i] : 0u;
    sm[t] = v; __syncthreads();
    for (int off = 1; off < 256; off <<= 1) {
        unsigned int x = (t >= off) ? sm[t - off] : 0u;
        __syncthreads();
        sm[t] += x;
        __syncthreads();
    }
    if (i < N) excl[i] = sm[t] - v;
    if (t == 255) bsum[blockIdx.x] = sm[255];
}

__global__ void k_scan2(const unsigned int* __restrict__ bsum, unsigned int* __restrict__ boff, int nb) {
    __shared__ unsigned int sm[256];
    int t = threadIdx.x;
    unsigned int v = (t < nb) ? bsum[t] : 0u;
    sm[t] = v; __syncthreads();
    for (int off = 1; off < 256; off <<= 1) {
        unsigned int x = (t >= off) ? sm[t - off] : 0u;
        __syncthreads();
        sm[t] += x;
        __syncthreads();
    }
    if (t < nb) boff[t] = sm[t] - v;
}

__global__ void k_scan3(unsigned int* __restrict__ rp, const unsigned int* __restrict__ boff, int N, int E) {
    int i = blockIdx.x * 256 + threadIdx.x;
    if (i < N) rp[i] += boff[i >> 8];
    if (i == 0) rp[N] = (unsigned int)E;
}

__global__ void k_scatter(const int* __restrict__ ei, const int* __restrict__ et, int E,
                          const unsigned int* __restrict__ rp, unsigned int* __restrict__ fill,
                          unsigned int* __restrict__ packed) {
    int e = blockIdx.x * blockDim.x + threadIdx.x;
    if (e < E) {
        int d = ei[e];
        unsigned int s = (unsigned int)ei[E + e];
        unsigned int tt = (unsigned int)et[e];
        unsigned int pos = rp[d] + atomicAdd(&fill[d], 1u);
        packed[pos] = s | (tt << 16);
    }
}

__global__ void k_dinv(const unsigned int* __restrict__ deg, float* __restrict__ dinv, int N) {
    int i = blockIdx.x * blockDim.x + threadIdx.x;
    if (i < N) {
        unsigned int d = deg[i];
        dinv[i] = (d > 0u) ? rsqrtf((float)d) : 0.f;
    }
}

// ---------------- BN stats + apply ----------------
__global__ void k_colstats(const unsigned short* __restrict__ h, int N,
                           float* __restrict__ sum, float* __restrict__ sumsq) {
    int c  = threadIdx.x & 127;
    int rq = threadIdx.x >> 7;
    float s = 0.f, q = 0.f;
    for (int r = blockIdx.x * 2 + rq; r < N; r += gridDim.x * 2) {
        float v = bf2f(h[(size_t)r * D + c]);
        s += v; q += v * v;
    }
    __shared__ float ss[256], qq[256];
    ss[threadIdx.x] = s; qq[threadIdx.x] = q;
    __syncthreads();
    if (rq == 0) {
        atomicAdd(&sum[c],   ss[threadIdx.x] + ss[threadIdx.x + 128]);
        atomicAdd(&sumsq[c], qq[threadIdx.x] + qq[threadIdx.x + 128]);
    }
}

__global__ void k_bnrelu(unsigned short* __restrict__ h, const float* __restrict__ sum,
                         const float* __restrict__ sumsq, const unsigned short* __restrict__ g,
                         const unsigned short* __restrict__ b, int N) {
    int i = blockIdx.x * blockDim.x + threadIdx.x;
    if (i < N * D) {
        int c = i & 127;
        float inv = 1.f / (float)N;
        float mean = sum[c] * inv;
        float var = fmaxf(sumsq[c] * inv - mean * mean, 0.f);
        float v = bf2f(h[i]);
        v = (v - mean) * rsqrtf(var + 1e-5f) * bf2f(g[c]) + bf2f(b[c]);
        h[i] = f2bf(fmaxf(v, 0.f));
    }
}

// ---------------- edge aggregation: one wave per dst node, online softmax ----------------
__global__ __launch_bounds__(256) void k_edge(
    const unsigned int* __restrict__ rp, const unsigned int* __restrict__ packed,
    const unsigned short* __restrict__ xl, const unsigned short* __restrict__ y,
    const float* __restrict__ dinv, unsigned short* __restrict__ z, int N, int RD)
{
    int lane = threadIdx.x & 63;
    int node = blockIdx.x * 4 + (threadIdx.x >> 6);
    node = __builtin_amdgcn_readfirstlane(node);
    if (node >= N) return;
    unsigned int beg = rp[node], end = rp[node + 1];
    int c2 = lane * 2;
    float g0 = 0.f, g1 = 0.f;
    float m0 = -INFINITY, m1 = -INFINITY;
    float d0 = 0.f, d1 = 0.f, s0 = 0.f, s1 = 0.f;
    for (unsigned int e = beg; e < end; ++e) {
        unsigned int p = packed[e];
        unsigned int s = p & 0xFFFFu;
        unsigned int tt = p >> 16;
        float ds = dinv[s];
        unsigned int xx = *((const unsigned int*)(xl + (size_t)s * D + c2));
        g0 += bf2f((unsigned short)(xx & 0xFFFFu)) * ds;
        g1 += bf2f((unsigned short)(xx >> 16)) * ds;
        unsigned int yy = *((const unsigned int*)(y + (size_t)s * RD + tt * D + c2));
        float v0 = bf2f((unsigned short)(yy & 0xFFFFu));
        float v1 = bf2f((unsigned short)(yy >> 16));
        float mn0 = fmaxf(m0, v0);
        float sc0 = __expf(m0 - mn0);
        float e0  = __expf(v0 - mn0);
        d0 = d0 * sc0 + e0; s0 = s0 * sc0 + v0 * e0; m0 = mn0;
        float mn1 = fmaxf(m1, v1);
        float sc1 = __expf(m1 - mn1);
        float e1  = __expf(v1 - mn1);
        d1 = d1 * sc1 + e1; s1 = s1 * sc1 + v1 * e1; m1 = mn1;
    }
    float dn = dinv[node];
    float msg0 = (d0 > 0.f) ? s0 / d0 : 0.f;
    float msg1 = (d1 > 0.f) ? s1 / d1 : 0.f;
    float z0 = g0 * dn + 0.1f * fmaxf(msg0, 0.f);
    float z1 = g1 * dn + 0.1f * fmaxf(msg1, 0.f);
    unsigned int o = ((unsigned int)f2bf(z0)) | (((unsigned int)f2bf(z1)) << 16);
    *((unsigned int*)(z + (size_t)node * D + c2)) = o;
}

// ---------------- final gather + exact GeLU (dtype-flag-dependent store) ----------------
__global__ void k_out(const unsigned short* __restrict__ h, const int* __restrict__ idx,
                      void* __restrict__ out, int NI, const int* __restrict__ flag) {
    int i = blockIdx.x * blockDim.x + threadIdx.x;
    if (i < NI * D) {
        int r = idx[i >> 7];
        float v = bf2f(h[(size_t)r * D + (i & 127)]);
        float gl = 0.5f * v * (1.f + erff(v * 0.70710678118654752f));
        if (*flag) ((float*)out)[i] = gl;
        else       ((unsigned short*)out)[i] = f2bf(gl);
    }
}

extern "C" void kernel_launch(void* const* d_in, const int* in_sizes, int n_in,
                              void* d_out, int out_size, void* d_ws, size_t ws_size,
                              hipStream_t stream)
{
    const int* ei  = (const int*)d_in[1];
    const int* idx = (const int*)d_in[2];
    const int* et  = (const int*)d_in[3];

    int N  = in_sizes[0] / D;            // 48758
    int E  = in_sizes[1] / 2;            // 780000
    int NI = in_sizes[2];                // 10000
    int L  = in_sizes[9] / (D * D);      // 2
    int R  = in_sizes[11] / (L * D * D); // 4
    int RD = R * D;

    char* ws = (char*)d_ws;
    size_t off = 0;
    auto alloc = [&](size_t bytes) -> char* {
        char* p = ws + off;
        off += (bytes + 255) & ~(size_t)255;
        return p;
    };
    unsigned short* h    = (unsigned short*)alloc((size_t)N * D * 2);
    unsigned short* xl   = (unsigned short*)alloc((size_t)N * D * 2);
    unsigned short* y    = (unsigned short*)alloc((size_t)N * RD * 2);
    unsigned short* z    = (unsigned short*)alloc((size_t)N * D * 2);
    unsigned short* xb   = (unsigned short*)alloc((size_t)N * D * 2);
    float*          dinv = (float*)alloc((size_t)N * 4);
    unsigned int*   cntd = (unsigned int*)alloc((size_t)N * 4);
    unsigned int*   degs = (unsigned int*)alloc((size_t)N * 4);
    unsigned int*   fill = (unsigned int*)alloc((size_t)N * 4);
    unsigned int*   rp   = (unsigned int*)alloc((size_t)(N + 1) * 4);
    unsigned int*   bsum = (unsigned int*)alloc(256 * 4);
    unsigned int*   boff = (unsigned int*)alloc(256 * 4);
    float*          csum = (float*)alloc(D * 4);
    float*          csq  = (float*)alloc(D * 4);
    int*            flag = (int*)alloc(256);
    unsigned int*   pckd = (unsigned int*)alloc((size_t)E * 4);
    // normalized bf16 weights
    unsigned short* w_proj = (unsigned short*)alloc((size_t)D * D * 2);
    unsigned short* b_proj = (unsigned short*)alloc((size_t)D * 2);
    unsigned short* g_bn   = (unsigned short*)alloc((size_t)D * 2);
    unsigned short* b_bn   = (unsigned short*)alloc((size_t)D * 2);
    unsigned short* w_in   = (unsigned short*)alloc((size_t)L * D * D * 2);
    unsigned short* b_in   = (unsigned short*)alloc((size_t)L * D * 2);
    unsigned short* w_rel  = (unsigned short*)alloc((size_t)L * R * D * D * 2);
    unsigned short* w_out  = (unsigned short*)alloc((size_t)L * D * D * 2);
    unsigned short* b_out  = (unsigned short*)alloc((size_t)L * D * 2);
    (void)ws_size; (void)n_in; (void)out_size;

    hipMemsetAsync(cntd, 0, (size_t)N * 4, stream);
    hipMemsetAsync(degs, 0, (size_t)N * 4, stream);
    hipMemsetAsync(fill, 0, (size_t)N * 4, stream);
    hipMemsetAsync(csum, 0, D * 4, stream);
    hipMemsetAsync(csq,  0, D * 4, stream);

    int eb = (E + 255) / 256;
    int nb = (N + 255) / 256;
    int gb = (N + 127) / 128;

    // dtype detect + input normalization to bf16
    k_detect<<<1, 256, 0, stream>>>((const unsigned short*)d_in[0], flag);
    struct { const void* src; unsigned short* dst; int n; } norm[] = {
        { d_in[0],  xb,     N * D },
        { d_in[5],  w_proj, D * D },
        { d_in[6],  b_proj, D },
        { d_in[7],  g_bn,   D },
        { d_in[8],  b_bn,   D },
        { d_in[9],  w_in,   L * D * D },
        { d_in[10], b_in,   L * D },
        { d_in[11], w_rel,  L * R * D * D },
        { d_in[12], w_out,  L * D * D },
        { d_in[13], b_out,  L * D },
    };
    for (auto& nrm : norm)
        k_norm<<<(nrm.n + 255) / 256, 256, 0, stream>>>(nrm.src, nrm.dst, nrm.n, flag);

    // CSR + degrees (independent of feature pipeline)
    k_count<<<eb, 256, 0, stream>>>(ei, E, cntd, degs);
    k_scan1<<<nb, 256, 0, stream>>>(cntd, rp, bsum, N);
    k_scan2<<<1, 256, 0, stream>>>(bsum, boff, nb);
    k_scan3<<<nb, 256, 0, stream>>>(rp, boff, N, E);
    k_scatter<<<eb, 256, 0, stream>>>(ei, et, E, rp, fill, pckd);
    k_dinv<<<nb, 256, 0, stream>>>(degs, dinv, N);

    // proj + BN + relu
    gemm128<<<gb, 256, 0, stream>>>(xb, w_proj, b_proj, h, N, D, 0);
    k_colstats<<<512, 256, 0, stream>>>(h, N, csum, csq);
    int ebn = (N * D + 255) / 256;
    k_bnrelu<<<ebn, 256, 0, stream>>>(h, csum, csq, g_bn, b_bn, N);

    for (int l = 0; l < L; ++l) {
        gemm128<<<gb, 256, 0, stream>>>(h, w_in + l * D * D, b_in + l * D, xl, N, D, 0);
        for (int r = 0; r < R; ++r)
            gemm128<<<gb, 256, 0, stream>>>(xl, w_rel + (size_t)(l * R + r) * D * D, nullptr, y, N, RD, r * D);
        int nb4 = (N + 3) / 4;
        k_edge<<<nb4, 256, 0, stream>>>(rp, pckd, xl, y, dinv, z, N, RD);
        gemm128<<<gb, 256, 0, stream>>>(z, w_out + l * D * D, b_out + l * D, h, N, D, 0);
    }

    int ob = (NI * D + 255) / 256;
    k_out<<<ob, 256, 0, stream>>>(h, idx, d_out, NI, flag);
}

// Round 3
// 561.965 us; speedup vs baseline: 1.1198x; 1.1198x over previous
//
#include <hip/hip_runtime.h>
#include <hip/hip_bf16.h>
#include <math.h>

#define D 128
#define DD (128 * 128)

typedef __attribute__((ext_vector_type(8))) short short8;
typedef __attribute__((ext_vector_type(4))) float f32x4;

__device__ __forceinline__ float bf2f(unsigned short u) {
    union { unsigned int i; float f; } x; x.i = ((unsigned int)u) << 16; return x.f;
}
__device__ __forceinline__ unsigned short f2bf(float f) {
    unsigned int i = __float_as_uint(f);
    unsigned int r = (i + 0x7FFFu + ((i >> 16) & 1u)) >> 16;  // RNE
    return (unsigned short)r;
}

// ---------------- dtype detect: fp32 read as shorts -> random exponent fields ----------------
__global__ void k_detect(const unsigned short* __restrict__ x, int* __restrict__ flag) {
    __shared__ int bad;
    if (threadIdx.x == 0) bad = 0;
    __syncthreads();
    unsigned int e = (x[threadIdx.x] >> 7) & 0xFFu;
    if (e < 100u || e > 140u) atomicAdd(&bad, 1);
    __syncthreads();
    if (threadIdx.x == 0) *flag = (bad > 48) ? 1 : 0;
}

// ---------------- normalize x to bf16 (vec4) ----------------
__global__ void k_normx(const void* __restrict__ in, unsigned short* __restrict__ out,
                        int n4, const int* __restrict__ flag) {
    int i = blockIdx.x * blockDim.x + threadIdx.x;
    if (i >= n4) return;
    if (*flag) {
        float4 v = ((const float4*)in)[i];
        uint2 o;
        o.x = (unsigned int)f2bf(v.x) | ((unsigned int)f2bf(v.y) << 16);
        o.y = (unsigned int)f2bf(v.z) | ((unsigned int)f2bf(v.w) << 16);
        ((uint2*)out)[i] = o;
    } else {
        ((uint2*)out)[i] = ((const uint2*)in)[i];
    }
}

// ---------------- normalize all 9 weight tensors into one contiguous bf16 region ----------------
__global__ void k_normw(const void* s0, const void* s1, const void* s2, const void* s3,
                        const void* s4, const void* s5, const void* s6, const void* s7,
                        const void* s8,
                        int o1, int o2, int o3, int o4, int o5, int o6, int o7, int o8,
                        int total, unsigned short* __restrict__ dst, const int* __restrict__ flag) {
    int i = blockIdx.x * blockDim.x + threadIdx.x;
    if (i >= total) return;
    const void* src; int base;
    if      (i < o1) { src = s0; base = 0;  }
    else if (i < o2) { src = s1; base = o1; }
    else if (i < o3) { src = s2; base = o2; }
    else if (i < o4) { src = s3; base = o3; }
    else if (i < o5) { src = s4; base = o4; }
    else if (i < o6) { src = s5; base = o5; }
    else if (i < o7) { src = s6; base = o6; }
    else if (i < o8) { src = s7; base = o7; }
    else             { src = s8; base = o8; }
    int li = i - base;
    dst[i] = (*flag) ? f2bf(((const float*)src)[li]) : ((const unsigned short*)src)[li];
}

// ---------------- shared GEMM core: 128x128 tile, 4 waves, 16x16x32 MFMA ----------------
__device__ __forceinline__ void gemm_core(
    const unsigned short* __restrict__ A, const unsigned short* __restrict__ W,
    int M, int blockRow, unsigned short* As, unsigned short* Wt, f32x4 (&acc)[2][8])
{
    int t = threadIdx.x;
    #pragma unroll
    for (int i = 0; i < 8; ++i) {
        int ch = t + i * 256;          // 0..2047
        int row = ch >> 4;
        int kc  = ch & 15;
        int grow = blockRow + row;
        uint4 v = make_uint4(0u, 0u, 0u, 0u);
        if (grow < M) v = *((const uint4*)(A + (size_t)grow * D + kc * 8));
        int kcs = kc ^ (row & 15);
        *((uint4*)&As[row * 128 + kcs * 8]) = v;
    }
    #pragma unroll
    for (int i = 0; i < 8; ++i) {
        int ch = t + i * 256;
        int k  = ch >> 4;
        int n0 = (ch & 15) * 8;
        uint4 v = *((const uint4*)(W + k * D + n0));
        const unsigned short* pv = (const unsigned short*)&v;
        int kc = k >> 3;
        int ko = k & 7;
        #pragma unroll
        for (int j = 0; j < 8; ++j) {
            int n = n0 + j;
            Wt[n * 128 + ((kc ^ (n & 15)) * 8) + ko] = pv[j];
        }
    }
    __syncthreads();

    int wave = t >> 6;
    int lane = t & 63;
    int quad = lane >> 4;
    int l16  = lane & 15;
    int rowbase = wave * 32;

    #pragma unroll
    for (int a = 0; a < 2; ++a)
        #pragma unroll
        for (int b = 0; b < 8; ++b) acc[a][b] = (f32x4){0.f, 0.f, 0.f, 0.f};

    #pragma unroll
    for (int ks = 0; ks < 4; ++ks) {
        int chunk = ks * 4 + quad;
        short8 af[2];
        short8 bf[8];
        #pragma unroll
        for (int rt = 0; rt < 2; ++rt) {
            int r = rowbase + rt * 16 + l16;
            af[rt] = *((const short8*)&As[r * 128 + (chunk ^ (r & 15)) * 8]);
        }
        #pragma unroll
        for (int ct = 0; ct < 8; ++ct) {
            int n = ct * 16 + l16;
            bf[ct] = *((const short8*)&Wt[n * 128 + (chunk ^ (n & 15)) * 8]);
        }
        #pragma unroll
        for (int rt = 0; rt < 2; ++rt)
            #pragma unroll
            for (int ct = 0; ct < 8; ++ct)
                acc[rt][ct] = __builtin_amdgcn_mfma_f32_16x16x32_bf16(af[rt], bf[ct], acc[rt][ct], 0, 0, 0);
    }
}

__device__ __forceinline__ void store_c(
    f32x4 (&acc)[2][8], const unsigned short* __restrict__ bias,
    unsigned short* __restrict__ C, int M, int blockRow, int ldc, int coloff)
{
    int t = threadIdx.x;
    int wave = t >> 6;
    int lane = t & 63;
    int quad = lane >> 4;
    int l16  = lane & 15;
    int rowbase = wave * 32;
    #pragma unroll
    for (int rt = 0; rt < 2; ++rt) {
        #pragma unroll
        for (int ct = 0; ct < 8; ++ct) {
            int col = ct * 16 + l16;
            float bv = bias ? bf2f(bias[col]) : 0.f;
            #pragma unroll
            for (int r = 0; r < 4; ++r) {
                int grow = blockRow + rowbase + rt * 16 + quad * 4 + r;
                if (grow < M) {
                    float v = acc[rt][ct][r] + bv;
                    C[(size_t)grow * ldc + coloff + col] = f2bf(v);
                }
            }
        }
    }
}

// ---------------- plain GEMM (layer-1 out) ----------------
__global__ __launch_bounds__(256) void gemm128(
    const unsigned short* __restrict__ A, const unsigned short* __restrict__ W,
    const unsigned short* __restrict__ bias, unsigned short* __restrict__ C,
    int M, int ldc, int coloff)
{
    __shared__ unsigned short As[DD];
    __shared__ unsigned short Wt[DD];
    f32x4 acc[2][8];
    gemm_core(A, W, M, blockIdx.x * 128, As, Wt, acc);
    store_c(acc, bias, C, M, blockIdx.x * 128, ldc, coloff);
}

// ---------------- proj GEMM + fused BN column stats ----------------
__global__ __launch_bounds__(256) void gemm_proj(
    const unsigned short* __restrict__ A, const unsigned short* __restrict__ W,
    const unsigned short* __restrict__ bias, unsigned short* __restrict__ C,
    int M, float* __restrict__ csum, float* __restrict__ csq)
{
    __shared__ unsigned short As[DD];
    __shared__ unsigned short Wt[DD];
    f32x4 acc[2][8];
    int blockRow = blockIdx.x * 128;
    gemm_core(A, W, M, blockRow, As, Wt, acc);

    int t = threadIdx.x;
    int wave = t >> 6;
    int lane = t & 63;
    int quad = lane >> 4;
    int l16  = lane & 15;
    int rowbase = wave * 32;
    #pragma unroll
    for (int ct = 0; ct < 8; ++ct) {
        int col = ct * 16 + l16;
        float bv = bf2f(bias[col]);
        float ps = 0.f, pq = 0.f;
        #pragma unroll
        for (int rt = 0; rt < 2; ++rt) {
            #pragma unroll
            for (int r = 0; r < 4; ++r) {
                int grow = blockRow + rowbase + rt * 16 + quad * 4 + r;
                if (grow < M) {
                    float v = acc[rt][ct][r] + bv;
                    C[(size_t)grow * D + col] = f2bf(v);
                    ps += v; pq += v * v;
                }
            }
        }
        ps += __shfl_xor(ps, 16, 64); ps += __shfl_xor(ps, 32, 64);
        pq += __shfl_xor(pq, 16, 64); pq += __shfl_xor(pq, 32, 64);
        if (quad == 0) {
            atomicAdd(&csum[col], ps);
            atomicAdd(&csq[col], pq);
        }
    }
}

// ---------------- weight composition: Wc[b] = win_w[l] @ wrel[b], bc[b] = win_b[l] @ wrel[b] ----------------
__global__ __launch_bounds__(256) void gemm_compose(
    const unsigned short* __restrict__ w_in, const unsigned short* __restrict__ wrel,
    const unsigned short* __restrict__ b_in, unsigned short* __restrict__ wc,
    unsigned short* __restrict__ bc)
{
    __shared__ unsigned short As[DD];
    __shared__ unsigned short Wt[DD];
    f32x4 acc[2][8];
    int b = blockIdx.x;          // l*4 + r
    int l = b >> 2;
    const unsigned short* A = w_in + (size_t)l * DD;
    const unsigned short* W = wrel + (size_t)b * DD;
    gemm_core(A, W, 128, 0, As, Wt, acc);
    store_c(acc, nullptr, wc + (size_t)b * DD, 128, 0, D, 0);
    int t = threadIdx.x;
    if (t < 128) {
        float s = 0.f;
        for (int k = 0; k < 128; ++k)
            s += bf2f(b_in[l * D + k]) * bf2f(W[k * D + t]);
        bc[b * D + t] = f2bf(s);
    }
}

// ---------------- fused per-layer GEMM: slice 0 -> xl = h@W1+b1; slices 1..4 -> y_r = h@Wc_r+bc_r ----------------
__global__ __launch_bounds__(256) void gemm_fused(
    const unsigned short* __restrict__ h, const unsigned short* __restrict__ w_in_l,
    const unsigned short* __restrict__ b_in_l, const unsigned short* __restrict__ wc_l,
    const unsigned short* __restrict__ bc_l, unsigned short* __restrict__ xl,
    unsigned short* __restrict__ y, int M)
{
    __shared__ unsigned short As[DD];
    __shared__ unsigned short Wt[DD];
    f32x4 acc[2][8];
    int slice = blockIdx.y;
    const unsigned short* W    = (slice == 0) ? w_in_l : wc_l + (size_t)(slice - 1) * DD;
    const unsigned short* bias = (slice == 0) ? b_in_l : bc_l + (slice - 1) * D;
    unsigned short* C = (slice == 0) ? xl : y;
    int ldc    = (slice == 0) ? D : 4 * D;
    int coloff = (slice == 0) ? 0 : (slice - 1) * D;
    gemm_core(h, W, M, blockIdx.x * 128, As, Wt, acc);
    store_c(acc, bias, C, M, blockIdx.x * 128, ldc, coloff);
}

// ---------------- final GEMM on gathered rows + exact GeLU epilogue ----------------
__global__ __launch_bounds__(256) void gemm_out(
    const unsigned short* __restrict__ A, const unsigned short* __restrict__ W,
    const unsigned short* __restrict__ bias, void* __restrict__ out,
    int M, const int* __restrict__ flag)
{
    __shared__ unsigned short As[DD];
    __shared__ unsigned short Wt[DD];
    f32x4 acc[2][8];
    int blockRow = blockIdx.x * 128;
    gemm_core(A, W, M, blockRow, As, Wt, acc);
    int fl = *flag;
    int t = threadIdx.x;
    int wave = t >> 6;
    int lane = t & 63;
    int quad = lane >> 4;
    int l16  = lane & 15;
    int rowbase = wave * 32;
    #pragma unroll
    for (int rt = 0; rt < 2; ++rt) {
        #pragma unroll
        for (int ct = 0; ct < 8; ++ct) {
            int col = ct * 16 + l16;
            float bv = bf2f(bias[col]);
            #pragma unroll
            for (int r = 0; r < 4; ++r) {
                int grow = blockRow + rowbase + rt * 16 + quad * 4 + r;
                if (grow < M) {
                    float v = acc[rt][ct][r] + bv;
                    float gl = 0.5f * v * (1.f + erff(v * 0.70710678118654752f));
                    size_t o = (size_t)grow * D + col;
                    if (fl) ((float*)out)[o] = gl;
                    else    ((unsigned short*)out)[o] = f2bf(gl);
                }
            }
        }
    }
}

// ---------------- CSR build ----------------
__global__ void k_count(const int* __restrict__ ei, int E,
                        unsigned int* __restrict__ cnt_dst, unsigned int* __restrict__ deg_src) {
    int e = blockIdx.x * blockDim.x + threadIdx.x;
    if (e < E) {
        atomicAdd(&cnt_dst[ei[e]], 1u);
        atomicAdd(&deg_src[ei[E + e]], 1u);
    }
}

__global__ void k_scan1(const unsigned int* __restrict__ cnt, unsigned int* __restrict__ excl,
                        unsigned int* __restrict__ bsum, int N) {
    __shared__ unsigned int sm[256];
    int t = threadIdx.x;
    int i = blockIdx.x * 256 + t;
    unsigned int v = (i < N) ? cnt[i] : 0u;
    sm[t] = v; __syncthreads();
    for (int off = 1; off < 256; off <<= 1) {
        unsigned int x = (t >= off) ? sm[t - off] : 0u;
        __syncthreads();
        sm[t] += x;
        __syncthreads();
    }
    if (i < N) excl[i] = sm[t] - v;
    if (t == 255) bsum[blockIdx.x] = sm[255];
}

__global__ void k_scan2(const unsigned int* __restrict__ bsum, unsigned int* __restrict__ boff, int nb) {
    __shared__ unsigned int sm[256];
    int t = threadIdx.x;
    unsigned int v = (t < nb) ? bsum[t] : 0u;
    sm[t] = v; __syncthreads();
    for (int off = 1; off < 256; off <<= 1) {
        unsigned int x = (t >= off) ? sm[t - off] : 0u;
        __syncthreads();
        sm[t] += x;
        __syncthreads();
    }
    if (t < nb) boff[t] = sm[t] - v;
}

__global__ void k_scan3(unsigned int* __restrict__ rp, const unsigned int* __restrict__ boff,
                        const unsigned int* __restrict__ degs, float* __restrict__ dinv,
                        int N, int E) {
    int i = blockIdx.x * 256 + threadIdx.x;
    if (i < N) {
        rp[i] += boff[i >> 8];
        unsigned int d = degs[i];
        dinv[i] = (d > 0u) ? rsqrtf((float)d) : 0.f;
    }
    if (i == 0) rp[N] = (unsigned int)E;
}

__global__ void k_scatter(const int* __restrict__ ei, const int* __restrict__ et, int E,
                          const unsigned int* __restrict__ rp, unsigned int* __restrict__ fill,
                          unsigned int* __restrict__ packed) {
    int e = blockIdx.x * blockDim.x + threadIdx.x;
    if (e < E) {
        int d = ei[e];
        unsigned int s = (unsigned int)ei[E + e];
        unsigned int tt = (unsigned int)et[e];
        unsigned int pos = rp[d] + atomicAdd(&fill[d], 1u);
        packed[pos] = s | (tt << 16);
    }
}

__global__ void k_flagidx(const int* __restrict__ idx, unsigned int* __restrict__ af, int NI) {
    int i = blockIdx.x * blockDim.x + threadIdx.x;
    if (i < NI) af[idx[i]] = 1u;
}

// ---------------- BN apply ----------------
__global__ void k_bnrelu(unsigned short* __restrict__ h, const float* __restrict__ sum,
                         const float* __restrict__ sumsq, const unsigned short* __restrict__ g,
                         const unsigned short* __restrict__ b, int N) {
    int i = blockIdx.x * blockDim.x + threadIdx.x;
    if (i < N * D) {
        int c = i & 127;
        float inv = 1.f / (float)N;
        float mean = sum[c] * inv;
        float var = fmaxf(sumsq[c] * inv - mean * mean, 0.f);
        float v = bf2f(h[i]);
        v = (v - mean) * rsqrtf(var + 1e-5f) * bf2f(g[c]) + bf2f(b[c]);
        h[i] = f2bf(fmaxf(v, 0.f));
    }
}

// ---------------- edge aggregation: 1 wave/node, 4 edges concurrent, 8 ch/lane ----------------
__global__ __launch_bounds__(256) void k_edge(
    const unsigned int* __restrict__ rp, const unsigned int* __restrict__ packed,
    const unsigned short* __restrict__ xl, const unsigned short* __restrict__ y,
    const float* __restrict__ dinv, unsigned short* __restrict__ z, int N, int RD,
    const unsigned int* __restrict__ af)
{
    int lane = threadIdx.x & 63;
    int node = blockIdx.x * 4 + (threadIdx.x >> 6);
    node = __builtin_amdgcn_readfirstlane(node);
    if (node >= N) return;
    if (af && af[node] == 0u) return;
    unsigned int beg = rp[node], end = rp[node + 1];
    int eg = lane >> 4;
    int cb = (lane & 15) * 8;
    float g[8], dd[8], ss[8];
    #pragma unroll
    for (int j = 0; j < 8; ++j) { g[j] = 0.f; dd[j] = 0.f; ss[j] = 0.f; }

    for (unsigned int e0 = beg; e0 < end; e0 += 4) {
        unsigned int e = e0 + (unsigned int)eg;
        bool valid = e < end;
        unsigned int p = packed[valid ? e : beg];
        unsigned int s = p & 0xFFFFu;
        unsigned int tt = p >> 16;
        float ds = valid ? dinv[s] : 0.f;
        uint4 xv = *((const uint4*)(xl + (size_t)s * D + cb));
        uint4 yv = *((const uint4*)(y + (size_t)s * RD + tt * D + cb));
        const unsigned int* xw = (const unsigned int*)&xv;
        const unsigned int* yw = (const unsigned int*)&yv;
        #pragma unroll
        for (int w = 0; w < 4; ++w) {
            float x0 = __uint_as_float(xw[w] << 16);
            float x1 = __uint_as_float(xw[w] & 0xFFFF0000u);
            float v0 = __uint_as_float(yw[w] << 16);
            float v1 = __uint_as_float(yw[w] & 0xFFFF0000u);
            int j0 = w * 2, j1 = w * 2 + 1;
            g[j0] = fmaf(x0, ds, g[j0]);
            g[j1] = fmaf(x1, ds, g[j1]);
            float e0f = __expf(v0); if (!valid) e0f = 0.f;
            float e1f = __expf(v1); if (!valid) e1f = 0.f;
            dd[j0] += e0f; dd[j1] += e1f;
            ss[j0] = fmaf(v0, e0f, ss[j0]);
            ss[j1] = fmaf(v1, e1f, ss[j1]);
        }
    }

    #pragma unroll
    for (int j = 0; j < 8; ++j) {
        g[j]  += __shfl_xor(g[j], 16, 64);  g[j]  += __shfl_xor(g[j], 32, 64);
        dd[j] += __shfl_xor(dd[j], 16, 64); dd[j] += __shfl_xor(dd[j], 32, 64);
        ss[j] += __shfl_xor(ss[j], 16, 64); ss[j] += __shfl_xor(ss[j], 32, 64);
    }
    if (eg == 0) {
        float dn = dinv[node];
        unsigned int o[4];
        #pragma unroll
        for (int w = 0; w < 4; ++w) {
            int j0 = w * 2, j1 = w * 2 + 1;
            float m0 = (dd[j0] > 0.f) ? ss[j0] / dd[j0] : 0.f;
            float m1 = (dd[j1] > 0.f) ? ss[j1] / dd[j1] : 0.f;
            float z0 = fmaf(g[j0], dn, 0.1f * fmaxf(m0, 0.f));
            float z1 = fmaf(g[j1], dn, 0.1f * fmaxf(m1, 0.f));
            o[w] = (unsigned int)f2bf(z0) | ((unsigned int)f2bf(z1) << 16);
        }
        *((uint4*)(z + (size_t)node * D + cb)) = *(uint4*)o;
    }
}

// ---------------- gather z rows at idx ----------------
__global__ void k_gather(const unsigned short* __restrict__ z, const int* __restrict__ idx,
                         unsigned short* __restrict__ zg, int NI) {
    int t = blockIdx.x * blockDim.x + threadIdx.x;
    if (t < NI * 16) {
        int row = idx[t >> 4];
        int ch = (t & 15) * 8;
        ((uint4*)zg)[t] = *((const uint4*)(z + (size_t)row * D + ch));
    }
}

extern "C" void kernel_launch(void* const* d_in, const int* in_sizes, int n_in,
                              void* d_out, int out_size, void* d_ws, size_t ws_size,
                              hipStream_t stream)
{
    const int* ei  = (const int*)d_in[1];
    const int* idx = (const int*)d_in[2];
    const int* et  = (const int*)d_in[3];

    int N  = in_sizes[0] / D;            // 48758
    int E  = in_sizes[1] / 2;            // 780000
    int NI = in_sizes[2];                // 10000
    int L  = in_sizes[9] / (D * D);      // 2
    int R  = in_sizes[11] / (L * D * D); // 4
    int RD = R * D;

    char* ws = (char*)d_ws;
    size_t off = 0;
    auto alloc = [&](size_t bytes) -> char* {
        char* p = ws + off;
        off += (bytes + 255) & ~(size_t)255;
        return p;
    };
    unsigned short* h    = (unsigned short*)alloc((size_t)N * D * 2);
    unsigned short* xl   = (unsigned short*)alloc((size_t)N * D * 2);
    unsigned short* y    = (unsigned short*)alloc((size_t)N * RD * 2);
    unsigned short* z    = (unsigned short*)alloc((size_t)N * D * 2);
    unsigned short* xb   = (unsigned short*)alloc((size_t)N * D * 2);
    unsigned short* zg   = (unsigned short*)alloc((size_t)NI * D * 2);
    float*          dinv = (float*)alloc((size_t)N * 4);
    unsigned int*   rp   = (unsigned int*)alloc((size_t)(N + 1) * 4);
    unsigned int*   bsum = (unsigned int*)alloc(256 * 4);
    unsigned int*   boff = (unsigned int*)alloc(256 * 4);
    int*            flag = (int*)alloc(256);
    unsigned int*   pckd = (unsigned int*)alloc((size_t)E * 4);
    // one contiguous zero region: cntd, degs, fill, af, csum, csq
    char* zero_base = alloc(((size_t)4 * N + 256) * 4);
    unsigned int* cntd = (unsigned int*)zero_base;
    unsigned int* degs = cntd + N;
    unsigned int* fill = degs + N;
    unsigned int* af   = fill + N;
    float*        csum = (float*)(af + N);
    float*        csq  = csum + 128;
    // contiguous bf16 weight region
    int o1 = D * D;                // w_proj
    int o2 = o1 + D;               // b_proj
    int o3 = o2 + D;               // bn_g
    int o4 = o3 + D;               // bn_b
    int o5 = o4 + L * D * D;       // w_in
    int o6 = o5 + L * D;           // b_in
    int o7 = o6 + L * R * D * D;   // w_rel
    int o8 = o7 + L * D * D;       // w_out
    int wt = o8 + L * D;           // b_out end
    unsigned short* wbase  = (unsigned short*)alloc((size_t)wt * 2);
    unsigned short* w_proj = wbase;
    unsigned short* b_proj = wbase + o1;
    unsigned short* g_bn   = wbase + o2;
    unsigned short* b_bn   = wbase + o3;
    unsigned short* w_in   = wbase + o4;
    unsigned short* b_in   = wbase + o5;
    unsigned short* w_rel  = wbase + o6;
    unsigned short* w_out  = wbase + o7;
    unsigned short* b_out  = wbase + o8;
    unsigned short* wc     = (unsigned short*)alloc((size_t)L * R * D * D * 2);
    unsigned short* bc     = (unsigned short*)alloc((size_t)L * R * D * 2);
    (void)ws_size; (void)n_in; (void)out_size;

    hipMemsetAsync(zero_base, 0, ((size_t)4 * N + 256) * 4, stream);

    int eb  = (E + 255) / 256;
    int nb  = (N + 255) / 256;
    int gb  = (N + 127) / 128;
    int gb2 = (NI + 127) / 128;
    int nb4 = (N + 3) / 4;

    // dtype detect + normalization
    k_detect<<<1, 256, 0, stream>>>((const unsigned short*)d_in[0], flag);
    int n4 = N * D / 4;
    k_normx<<<(n4 + 255) / 256, 256, 0, stream>>>(d_in[0], xb, n4, flag);
    k_normw<<<(wt + 255) / 256, 256, 0, stream>>>(
        d_in[5], d_in[6], d_in[7], d_in[8], d_in[9], d_in[10], d_in[11], d_in[12], d_in[13],
        o1, o2, o3, o4, o5, o6, o7, o8, wt, wbase, flag);

    // CSR + degrees + dst-flags
    k_count<<<eb, 256, 0, stream>>>(ei, E, cntd, degs);
    k_scan1<<<nb, 256, 0, stream>>>(cntd, rp, bsum, N);
    k_scan2<<<1, 256, 0, stream>>>(bsum, boff, nb);
    k_scan3<<<nb, 256, 0, stream>>>(rp, boff, degs, dinv, N, E);
    k_scatter<<<eb, 256, 0, stream>>>(ei, et, E, rp, fill, pckd);
    k_flagidx<<<(NI + 255) / 256, 256, 0, stream>>>(idx, af, NI);

    // composed weights (all L*R at once)
    gemm_compose<<<L * R, 256, 0, stream>>>(w_in, w_rel, b_in, wc, bc);

    // proj + BN + relu
    gemm_proj<<<gb, 256, 0, stream>>>(xb, w_proj, b_proj, h, N, csum, csq);
    k_bnrelu<<<(N * D + 255) / 256, 256, 0, stream>>>(h, csum, csq, g_bn, b_bn, N);

    // layer 0 (full graph)
    gemm_fused<<<dim3(gb, 1 + R), 256, 0, stream>>>(h, w_in, b_in, wc, bc, xl, y, N);
    k_edge<<<nb4, 256, 0, stream>>>(rp, pckd, xl, y, dinv, z, N, RD, nullptr);
    gemm128<<<gb, 256, 0, stream>>>(z, w_out, b_out, h, N, D, 0);

    // layer 1 (aggregate only dst in idx)
    gemm_fused<<<dim3(gb, 1 + R), 256, 0, stream>>>(h, w_in + DD, b_in + D, wc + (size_t)R * DD, bc + R * D, xl, y, N);
    k_edge<<<nb4, 256, 0, stream>>>(rp, pckd, xl, y, dinv, z, N, RD, af);

    // gather idx rows, final GEMM + GeLU
    k_gather<<<(NI * 16 + 255) / 256, 256, 0, stream>>>(z, idx, zg, NI);
    gemm_out<<<gb2, 256, 0, stream>>>(zg, w_out + DD, b_out + D, d_out, NI, flag);
}

// Round 4
// 468.167 us; speedup vs baseline: 1.3441x; 1.2004x over previous
//
#include <hip/hip_runtime.h>
#include <hip/hip_bf16.h>
#include <math.h>

#define D 128
#define DD (128 * 128)

typedef __attribute__((ext_vector_type(8))) short short8;
typedef __attribute__((ext_vector_type(4))) float f32x4;

__device__ __forceinline__ float bf2f(unsigned short u) {
    union { unsigned int i; float f; } x; x.i = ((unsigned int)u) << 16; return x.f;
}
__device__ __forceinline__ unsigned short f2bf(float f) {
    unsigned int i = __float_as_uint(f);
    unsigned int r = (i + 0x7FFFu + ((i >> 16) & 1u)) >> 16;  // RNE
    return (unsigned short)r;
}

// ---------------- dtype detect ----------------
__global__ void k_detect(const unsigned short* __restrict__ x, int* __restrict__ flag) {
    __shared__ int bad;
    if (threadIdx.x == 0) bad = 0;
    __syncthreads();
    unsigned int e = (x[threadIdx.x] >> 7) & 0xFFu;
    if (e < 100u || e > 140u) atomicAdd(&bad, 1);
    __syncthreads();
    if (threadIdx.x == 0) *flag = (bad > 48) ? 1 : 0;
}

// ---------------- normalize x to bf16 (vec4) ----------------
__global__ void k_normx(const void* __restrict__ in, unsigned short* __restrict__ out,
                        int n4, const int* __restrict__ flag) {
    int i = blockIdx.x * blockDim.x + threadIdx.x;
    if (i >= n4) return;
    if (*flag) {
        float4 v = ((const float4*)in)[i];
        uint2 o;
        o.x = (unsigned int)f2bf(v.x) | ((unsigned int)f2bf(v.y) << 16);
        o.y = (unsigned int)f2bf(v.z) | ((unsigned int)f2bf(v.w) << 16);
        ((uint2*)out)[i] = o;
    } else {
        ((uint2*)out)[i] = ((const uint2*)in)[i];
    }
}

// ---------------- normalize all 9 weight tensors into one contiguous bf16 region ----------------
__global__ void k_normw(const void* s0, const void* s1, const void* s2, const void* s3,
                        const void* s4, const void* s5, const void* s6, const void* s7,
                        const void* s8,
                        int o1, int o2, int o3, int o4, int o5, int o6, int o7, int o8,
                        int total, unsigned short* __restrict__ dst, const int* __restrict__ flag) {
    int i = blockIdx.x * blockDim.x + threadIdx.x;
    if (i >= total) return;
    const void* src; int base;
    if      (i < o1) { src = s0; base = 0;  }
    else if (i < o2) { src = s1; base = o1; }
    else if (i < o3) { src = s2; base = o2; }
    else if (i < o4) { src = s3; base = o3; }
    else if (i < o5) { src = s4; base = o4; }
    else if (i < o6) { src = s5; base = o5; }
    else if (i < o7) { src = s6; base = o6; }
    else if (i < o8) { src = s7; base = o7; }
    else             { src = s8; base = o8; }
    int li = i - base;
    dst[i] = (*flag) ? f2bf(((const float*)src)[li]) : ((const unsigned short*)src)[li];
}

// ---------------- OLD gemm core (LDS transpose) — only used by gemm_compose (8 blocks) ----------------
__device__ __forceinline__ void gemm_core(
    const unsigned short* __restrict__ A, const unsigned short* __restrict__ W,
    int M, int blockRow, unsigned short* As, unsigned short* Wt, f32x4 (&acc)[2][8])
{
    int t = threadIdx.x;
    #pragma unroll
    for (int i = 0; i < 8; ++i) {
        int ch = t + i * 256;
        int row = ch >> 4;
        int kc  = ch & 15;
        int grow = blockRow + row;
        uint4 v = make_uint4(0u, 0u, 0u, 0u);
        if (grow < M) v = *((const uint4*)(A + (size_t)grow * D + kc * 8));
        int kcs = kc ^ (row & 15);
        *((uint4*)&As[row * 128 + kcs * 8]) = v;
    }
    #pragma unroll
    for (int i = 0; i < 8; ++i) {
        int ch = t + i * 256;
        int k  = ch >> 4;
        int n0 = (ch & 15) * 8;
        uint4 v = *((const uint4*)(W + k * D + n0));
        const unsigned short* pv = (const unsigned short*)&v;
        int kc = k >> 3;
        int ko = k & 7;
        #pragma unroll
        for (int j = 0; j < 8; ++j) {
            int n = n0 + j;
            Wt[n * 128 + ((kc ^ (n & 15)) * 8) + ko] = pv[j];
        }
    }
    __syncthreads();

    int wave = t >> 6;
    int lane = t & 63;
    int quad = lane >> 4;
    int l16  = lane & 15;
    int rowbase = wave * 32;

    #pragma unroll
    for (int a = 0; a < 2; ++a)
        #pragma unroll
        for (int b = 0; b < 8; ++b) acc[a][b] = (f32x4){0.f, 0.f, 0.f, 0.f};

    #pragma unroll
    for (int ks = 0; ks < 4; ++ks) {
        int chunk = ks * 4 + quad;
        short8 af[2];
        short8 bf[8];
        #pragma unroll
        for (int rt = 0; rt < 2; ++rt) {
            int r = rowbase + rt * 16 + l16;
            af[rt] = *((const short8*)&As[r * 128 + (chunk ^ (r & 15)) * 8]);
        }
        #pragma unroll
        for (int ct = 0; ct < 8; ++ct) {
            int n = ct * 16 + l16;
            bf[ct] = *((const short8*)&Wt[n * 128 + (chunk ^ (n & 15)) * 8]);
        }
        #pragma unroll
        for (int rt = 0; rt < 2; ++rt)
            #pragma unroll
            for (int ct = 0; ct < 8; ++ct)
                acc[rt][ct] = __builtin_amdgcn_mfma_f32_16x16x32_bf16(af[rt], bf[ct], acc[rt][ct], 0, 0, 0);
    }
}

__device__ __forceinline__ void store_c(
    f32x4 (&acc)[2][8], const unsigned short* __restrict__ bias,
    unsigned short* __restrict__ C, int M, int blockRow, int ldc, int coloff)
{
    int t = threadIdx.x;
    int wave = t >> 6;
    int lane = t & 63;
    int quad = lane >> 4;
    int l16  = lane & 15;
    int rowbase = wave * 32;
    #pragma unroll
    for (int rt = 0; rt < 2; ++rt) {
        #pragma unroll
        for (int ct = 0; ct < 8; ++ct) {
            int col = ct * 16 + l16;
            float bv = bias ? bf2f(bias[col]) : 0.f;
            #pragma unroll
            for (int r = 0; r < 4; ++r) {
                int grow = blockRow + rowbase + rt * 16 + quad * 4 + r;
                if (grow < M) {
                    float v = acc[rt][ct][r] + bv;
                    C[(size_t)grow * ldc + coloff + col] = f2bf(v);
                }
            }
        }
    }
}

// ---------------- weight composition: Wc[b] = win_w[l] @ wrel[b], bc[b] = win_b[l] @ wrel[b] ----------------
__global__ __launch_bounds__(256) void gemm_compose(
    const unsigned short* __restrict__ w_in, const unsigned short* __restrict__ wrel,
    const unsigned short* __restrict__ b_in, unsigned short* __restrict__ wc,
    unsigned short* __restrict__ bc)
{
    __shared__ unsigned short As[DD];
    __shared__ unsigned short Wt[DD];
    f32x4 acc[2][8];
    int b = blockIdx.x;          // l*4 + r
    int l = b >> 2;
    const unsigned short* A = w_in + (size_t)l * DD;
    const unsigned short* W = wrel + (size_t)b * DD;
    gemm_core(A, W, 128, 0, As, Wt, acc);
    store_c(acc, nullptr, wc + (size_t)b * DD, 128, 0, D, 0);
    int t = threadIdx.x;
    if (t < 128) {
        float s = 0.f;
        for (int k = 0; k < 128; ++k)
            s += bf2f(b_in[l * D + k]) * bf2f(W[k * D + t]);
        bc[b * D + t] = f2bf(s);
    }
}

// ---------------- pre-transpose + swizzle 13 weight mats: wtg[m][n*128 + (kc^(n&15))*8 + ko] = W[k][n] ----------------
__global__ __launch_bounds__(256) void k_prepw(
    const unsigned short* __restrict__ wbase, const unsigned short* __restrict__ wc,
    unsigned short* __restrict__ wtg, int o4, int o7)
{
    int m = blockIdx.x >> 3;
    int sub = blockIdx.x & 7;
    const unsigned short* src;
    if (m == 0)       src = wbase;                         // w_proj
    else if (m <= 2)  src = wbase + o4 + (m - 1) * DD;     // w_in[l]
    else if (m <= 10) src = wc + (size_t)(m - 3) * DD;     // composed wc[l*4+r]
    else              src = wbase + o7 + (m - 11) * DD;    // w_out[l]
    int c = sub * 256 + threadIdx.x;   // 0..2047
    int n = c >> 4;
    int kc = c & 15;
    unsigned short tmp[8];
    #pragma unroll
    for (int ko = 0; ko < 8; ++ko) tmp[ko] = src[(kc * 8 + ko) * 128 + n];
    *((uint4*)(wtg + (size_t)m * DD + n * 128 + ((kc ^ (n & 15)) * 8))) = *(uint4*)tmp;
}

// ---------------- FAST gemm core: W pre-transposed/swizzled in global, A direct from global ----------------
__device__ __forceinline__ void gemm_core_fast(
    const unsigned short* __restrict__ A,
    const unsigned short* __restrict__ Wt_g,
    int M, int blockRow, const int* __restrict__ rowmap,
    unsigned short* Wt, f32x4 (&acc)[2][8])
{
    int t = threadIdx.x;
    #pragma unroll
    for (int i = 0; i < 8; ++i)
        ((uint4*)Wt)[t + i * 256] = ((const uint4*)Wt_g)[t + i * 256];

    int wave = t >> 6, lane = t & 63, quad = lane >> 4, l16 = lane & 15;
    int rowbase = blockRow + wave * 32;
    int r0 = min(rowbase + l16, M - 1);
    int r1 = min(rowbase + 16 + l16, M - 1);
    if (rowmap) { r0 = rowmap[r0]; r1 = rowmap[r1]; }
    const unsigned short* a0 = A + (size_t)r0 * D;
    const unsigned short* a1 = A + (size_t)r1 * D;
    short8 af[2][4];
    #pragma unroll
    for (int ks = 0; ks < 4; ++ks) {
        int chunk = ks * 4 + quad;
        af[0][ks] = *((const short8*)(a0 + chunk * 8));
        af[1][ks] = *((const short8*)(a1 + chunk * 8));
    }
    #pragma unroll
    for (int a = 0; a < 2; ++a)
        #pragma unroll
        for (int b = 0; b < 8; ++b) acc[a][b] = (f32x4){0.f, 0.f, 0.f, 0.f};
    __syncthreads();
    #pragma unroll
    for (int ks = 0; ks < 4; ++ks) {
        int chunk = ks * 4 + quad;
        short8 bf[8];
        #pragma unroll
        for (int ct = 0; ct < 8; ++ct)
            bf[ct] = *((const short8*)&Wt[(ct * 16 + l16) * 128 + ((chunk ^ l16) * 8)]);
        #pragma unroll
        for (int rt = 0; rt < 2; ++rt)
            #pragma unroll
            for (int ct = 0; ct < 8; ++ct)
                acc[rt][ct] = __builtin_amdgcn_mfma_f32_16x16x32_bf16(af[rt][ks], bf[ct], acc[rt][ct], 0, 0, 0);
    }
}

// ---------------- plain fast GEMM ----------------
__global__ __launch_bounds__(256) void gemm_fast(
    const unsigned short* __restrict__ A, const unsigned short* __restrict__ Wt_g,
    const unsigned short* __restrict__ bias, unsigned short* __restrict__ C,
    int M, int ldc, int coloff)
{
    __shared__ unsigned short Wt[DD];
    f32x4 acc[2][8];
    gemm_core_fast(A, Wt_g, M, blockIdx.x * 128, nullptr, Wt, acc);
    store_c(acc, bias, C, M, blockIdx.x * 128, ldc, coloff);
}

// ---------------- proj GEMM + per-block BN partial stats (no atomics) ----------------
__global__ __launch_bounds__(256) void gemm_proj(
    const unsigned short* __restrict__ A, const unsigned short* __restrict__ Wt_g,
    const unsigned short* __restrict__ bias, unsigned short* __restrict__ C,
    int M, float* __restrict__ psum, float* __restrict__ psq)
{
    __shared__ unsigned short Wt[DD];
    __shared__ float smS[4][128], smQ[4][128];
    f32x4 acc[2][8];
    int blockRow = blockIdx.x * 128;
    gemm_core_fast(A, Wt_g, M, blockRow, nullptr, Wt, acc);

    int t = threadIdx.x;
    int wave = t >> 6, lane = t & 63, quad = lane >> 4, l16 = lane & 15;
    int rowbase = wave * 32;
    #pragma unroll
    for (int ct = 0; ct < 8; ++ct) {
        int col = ct * 16 + l16;
        float bv = bf2f(bias[col]);
        float ps = 0.f, pq = 0.f;
        #pragma unroll
        for (int rt = 0; rt < 2; ++rt) {
            #pragma unroll
            for (int r = 0; r < 4; ++r) {
                int grow = blockRow + rowbase + rt * 16 + quad * 4 + r;
                if (grow < M) {
                    float v = acc[rt][ct][r] + bv;
                    C[(size_t)grow * D + col] = f2bf(v);
                    ps += v; pq += v * v;
                }
            }
        }
        ps += __shfl_xor(ps, 16, 64); ps += __shfl_xor(ps, 32, 64);
        pq += __shfl_xor(pq, 16, 64); pq += __shfl_xor(pq, 32, 64);
        if (quad == 0) { smS[wave][col] = ps; smQ[wave][col] = pq; }
    }
    __syncthreads();
    if (t < 128) {
        float s = smS[0][t] + smS[1][t] + smS[2][t] + smS[3][t];
        float q = smQ[0][t] + smQ[1][t] + smQ[2][t] + smQ[3][t];
        psum[blockIdx.x * 128 + t] = s;
        psq[blockIdx.x * 128 + t] = q;
    }
}

// ---------------- fused per-layer GEMM: slice 0 -> xl; slices 1..4 -> y_r ----------------
__global__ __launch_bounds__(256) void gemm_fused(
    const unsigned short* __restrict__ h, const unsigned short* __restrict__ wtg,
    const unsigned short* __restrict__ b_in_l, const unsigned short* __restrict__ bc_l,
    unsigned short* __restrict__ xl, unsigned short* __restrict__ y, int M, int l)
{
    __shared__ unsigned short Wt[DD];
    f32x4 acc[2][8];
    int slice = blockIdx.y;
    int m = (slice == 0) ? (1 + l) : (3 + l * 4 + slice - 1);
    const unsigned short* bias = (slice == 0) ? b_in_l : bc_l + (slice - 1) * D;
    unsigned short* C = (slice == 0) ? xl : y;
    int ldc    = (slice == 0) ? D : 4 * D;
    int coloff = (slice == 0) ? 0 : (slice - 1) * D;
    gemm_core_fast(h, wtg + (size_t)m * DD, M, blockIdx.x * 128, nullptr, Wt, acc);
    store_c(acc, bias, C, M, blockIdx.x * 128, ldc, coloff);
}

// ---------------- final GEMM: A rows gathered via idx, exact GeLU epilogue ----------------
__global__ __launch_bounds__(256) void gemm_out(
    const unsigned short* __restrict__ z, const unsigned short* __restrict__ Wt_g,
    const unsigned short* __restrict__ bias, void* __restrict__ out,
    int M, const int* __restrict__ idx, const int* __restrict__ flag)
{
    __shared__ unsigned short Wt[DD];
    f32x4 acc[2][8];
    int blockRow = blockIdx.x * 128;
    gemm_core_fast(z, Wt_g, M, blockRow, idx, Wt, acc);
    int fl = *flag;
    int t = threadIdx.x;
    int wave = t >> 6, lane = t & 63, quad = lane >> 4, l16 = lane & 15;
    int rowbase = wave * 32;
    #pragma unroll
    for (int rt = 0; rt < 2; ++rt) {
        #pragma unroll
        for (int ct = 0; ct < 8; ++ct) {
            int col = ct * 16 + l16;
            float bv = bf2f(bias[col]);
            #pragma unroll
            for (int r = 0; r < 4; ++r) {
                int grow = blockRow + rowbase + rt * 16 + quad * 4 + r;
                if (grow < M) {
                    float v = acc[rt][ct][r] + bv;
                    float gl = 0.5f * v * (1.f + erff(v * 0.70710678118654752f));
                    size_t o = (size_t)grow * D + col;
                    if (fl) ((float*)out)[o] = gl;
                    else    ((unsigned short*)out)[o] = f2bf(gl);
                }
            }
        }
    }
}

// ---------------- CSR build (+ idx flags) ----------------
__global__ void k_count(const int* __restrict__ ei, int E,
                        unsigned int* __restrict__ cnt_dst, unsigned int* __restrict__ deg_src,
                        const int* __restrict__ idx, unsigned int* __restrict__ af, int NI) {
    int e = blockIdx.x * blockDim.x + threadIdx.x;
    if (e < E) {
        atomicAdd(&cnt_dst[ei[e]], 1u);
        atomicAdd(&deg_src[ei[E + e]], 1u);
    }
    if (e < NI) af[idx[e]] = 1u;
}

__global__ void k_scan1(const unsigned int* __restrict__ cnt, unsigned int* __restrict__ excl,
                        unsigned int* __restrict__ bsum, int N) {
    __shared__ unsigned int sm[256];
    int t = threadIdx.x;
    int i = blockIdx.x * 256 + t;
    unsigned int v = (i < N) ? cnt[i] : 0u;
    sm[t] = v; __syncthreads();
    for (int off = 1; off < 256; off <<= 1) {
        unsigned int x = (t >= off) ? sm[t - off] : 0u;
        __syncthreads();
        sm[t] += x;
        __syncthreads();
    }
    if (i < N) excl[i] = sm[t] - v;
    if (t == 255) bsum[blockIdx.x] = sm[255];
}

__global__ void k_scan2(const unsigned int* __restrict__ bsum, unsigned int* __restrict__ boff, int nb) {
    __shared__ unsigned int sm[256];
    int t = threadIdx.x;
    unsigned int v = (t < nb) ? bsum[t] : 0u;
    sm[t] = v; __syncthreads();
    for (int off = 1; off < 256; off <<= 1) {
        unsigned int x = (t >= off) ? sm[t - off] : 0u;
        __syncthreads();
        sm[t] += x;
        __syncthreads();
    }
    if (t < nb) boff[t] = sm[t] - v;
}

__global__ void k_scan3(unsigned int* __restrict__ rp, const unsigned int* __restrict__ boff,
                        const unsigned int* __restrict__ degs, float* __restrict__ dinv,
                        int N, int E) {
    int i = blockIdx.x * 256 + threadIdx.x;
    if (i < N) {
        rp[i] += boff[i >> 8];
        unsigned int d = degs[i];
        dinv[i] = (d > 0u) ? rsqrtf((float)d) : 0.f;
    }
    if (i == 0) rp[N] = (unsigned int)E;
}

__global__ void k_scatter(const int* __restrict__ ei, const int* __restrict__ et, int E,
                          const unsigned int* __restrict__ rp, unsigned int* __restrict__ fill,
                          unsigned int* __restrict__ packed) {
    int e = blockIdx.x * blockDim.x + threadIdx.x;
    if (e < E) {
        int d = ei[e];
        unsigned int s = (unsigned int)ei[E + e];
        unsigned int tt = (unsigned int)et[e];
        unsigned int pos = rp[d] + atomicAdd(&fill[d], 1u);
        packed[pos] = s | (tt << 16);
    }
}

// ---------------- BN stats reduce (1 block) ----------------
__global__ void k_bnstats(const float* __restrict__ psum, const float* __restrict__ psq,
                          int nb, int N, const unsigned short* __restrict__ g,
                          const unsigned short* __restrict__ b,
                          float* __restrict__ scale, float* __restrict__ shift) {
    int col = threadIdx.x & 127, h = threadIdx.x >> 7;
    float s = 0.f, q = 0.f;
    for (int i = h; i < nb; i += 2) { s += psum[i * 128 + col]; q += psq[i * 128 + col]; }
    __shared__ float sS[256], sQ[256];
    sS[threadIdx.x] = s; sQ[threadIdx.x] = q;
    __syncthreads();
    if (h == 0) {
        s = sS[col] + sS[col + 128];
        q = sQ[col] + sQ[col + 128];
        float inv = 1.f / (float)N;
        float mean = s * inv;
        float var = fmaxf(q * inv - mean * mean, 0.f);
        float sc = rsqrtf(var + 1e-5f) * bf2f(g[col]);
        scale[col] = sc;
        shift[col] = bf2f(b[col]) - mean * sc;
    }
}

// ---------------- BN apply + relu (vec 8 shorts/thread) ----------------
__global__ void k_bnrelu(unsigned short* __restrict__ h, const float* __restrict__ scale,
                         const float* __restrict__ shift, int n8) {
    int i = blockIdx.x * blockDim.x + threadIdx.x;
    if (i >= n8) return;
    int cb = (i & 15) * 8;
    uint4 v = ((uint4*)h)[i];
    unsigned int* w = (unsigned int*)&v;
    #pragma unroll
    for (int j = 0; j < 4; ++j) {
        int c = cb + j * 2;
        float v0 = __uint_as_float(w[j] << 16);
        float v1 = __uint_as_float(w[j] & 0xFFFF0000u);
        v0 = fmaxf(fmaf(v0, scale[c], shift[c]), 0.f);
        v1 = fmaxf(fmaf(v1, scale[c + 1], shift[c + 1]), 0.f);
        w[j] = (unsigned int)f2bf(v0) | ((unsigned int)f2bf(v1) << 16);
    }
    ((uint4*)h)[i] = v;
}

// ---------------- edge aggregation: 1 wave/node, 4 edges concurrent, 8 ch/lane ----------------
__global__ __launch_bounds__(256) void k_edge(
    const unsigned int* __restrict__ rp, const unsigned int* __restrict__ packed,
    const unsigned short* __restrict__ xl, const unsigned short* __restrict__ y,
    const float* __restrict__ dinv, unsigned short* __restrict__ z, int N, int RD,
    const unsigned int* __restrict__ af)
{
    int lane = threadIdx.x & 63;
    int node = blockIdx.x * 4 + (threadIdx.x >> 6);
    node = __builtin_amdgcn_readfirstlane(node);
    if (node >= N) return;
    if (af && af[node] == 0u) return;
    unsigned int beg = rp[node], end = rp[node + 1];
    int eg = lane >> 4;
    int cb = (lane & 15) * 8;
    float g[8], dd[8], ss[8];
    #pragma unroll
    for (int j = 0; j < 8; ++j) { g[j] = 0.f; dd[j] = 0.f; ss[j] = 0.f; }

    for (unsigned int e0 = beg; e0 < end; e0 += 4) {
        unsigned int e = e0 + (unsigned int)eg;
        bool valid = e < end;
        unsigned int p = packed[valid ? e : beg];
        unsigned int s = p & 0xFFFFu;
        unsigned int tt = p >> 16;
        float ds = valid ? dinv[s] : 0.f;
        uint4 xv = *((const uint4*)(xl + (size_t)s * D + cb));
        uint4 yv = *((const uint4*)(y + (size_t)s * RD + tt * D + cb));
        const unsigned int* xw = (const unsigned int*)&xv;
        const unsigned int* yw = (const unsigned int*)&yv;
        #pragma unroll
        for (int w = 0; w < 4; ++w) {
            float x0 = __uint_as_float(xw[w] << 16);
            float x1 = __uint_as_float(xw[w] & 0xFFFF0000u);
            float v0 = __uint_as_float(yw[w] << 16);
            float v1 = __uint_as_float(yw[w] & 0xFFFF0000u);
            int j0 = w * 2, j1 = w * 2 + 1;
            g[j0] = fmaf(x0, ds, g[j0]);
            g[j1] = fmaf(x1, ds, g[j1]);
            float e0f = __expf(v0); if (!valid) e0f = 0.f;
            float e1f = __expf(v1); if (!valid) e1f = 0.f;
            dd[j0] += e0f; dd[j1] += e1f;
            ss[j0] = fmaf(v0, e0f, ss[j0]);
            ss[j1] = fmaf(v1, e1f, ss[j1]);
        }
    }

    #pragma unroll
    for (int j = 0; j < 8; ++j) {
        g[j]  += __shfl_xor(g[j], 16, 64);  g[j]  += __shfl_xor(g[j], 32, 64);
        dd[j] += __shfl_xor(dd[j], 16, 64); dd[j] += __shfl_xor(dd[j], 32, 64);
        ss[j] += __shfl_xor(ss[j], 16, 64); ss[j] += __shfl_xor(ss[j], 32, 64);
    }
    if (eg == 0) {
        float dn = dinv[node];
        unsigned int o[4];
        #pragma unroll
        for (int w = 0; w < 4; ++w) {
            int j0 = w * 2, j1 = w * 2 + 1;
            float m0 = (dd[j0] > 0.f) ? ss[j0] / dd[j0] : 0.f;
            float m1 = (dd[j1] > 0.f) ? ss[j1] / dd[j1] : 0.f;
            float z0 = fmaf(g[j0], dn, 0.1f * fmaxf(m0, 0.f));
            float z1 = fmaf(g[j1], dn, 0.1f * fmaxf(m1, 0.f));
            o[w] = (unsigned int)f2bf(z0) | ((unsigned int)f2bf(z1) << 16);
        }
        *((uint4*)(z + (size_t)node * D + cb)) = *(uint4*)o;
    }
}

extern "C" void kernel_launch(void* const* d_in, const int* in_sizes, int n_in,
                              void* d_out, int out_size, void* d_ws, size_t ws_size,
                              hipStream_t stream)
{
    const int* ei  = (const int*)d_in[1];
    const int* idx = (const int*)d_in[2];
    const int* et  = (const int*)d_in[3];

    int N  = in_sizes[0] / D;            // 48758
    int E  = in_sizes[1] / 2;            // 780000
    int NI = in_sizes[2];                // 10000
    int L  = in_sizes[9] / (D * D);      // 2
    int R  = in_sizes[11] / (L * D * D); // 4
    int RD = R * D;

    char* ws = (char*)d_ws;
    size_t off = 0;
    auto alloc = [&](size_t bytes) -> char* {
        char* p = ws + off;
        off += (bytes + 255) & ~(size_t)255;
        return p;
    };
    unsigned short* h    = (unsigned short*)alloc((size_t)N * D * 2);
    unsigned short* xl   = (unsigned short*)alloc((size_t)N * D * 2);
    unsigned short* y    = (unsigned short*)alloc((size_t)N * RD * 2);
    unsigned short* z    = (unsigned short*)alloc((size_t)N * D * 2);
    unsigned short* xb   = (unsigned short*)alloc((size_t)N * D * 2);
    float*          dinv = (float*)alloc((size_t)N * 4);
    unsigned int*   rp   = (unsigned int*)alloc((size_t)(N + 1) * 4);
    unsigned int*   bsum = (unsigned int*)alloc(256 * 4);
    unsigned int*   boff = (unsigned int*)alloc(256 * 4);
    int*            flag = (int*)alloc(256);
    unsigned int*   pckd = (unsigned int*)alloc((size_t)E * 4);
    int gb  = (N + 127) / 128;
    float*          psum = (float*)alloc((size_t)gb * 128 * 4);
    float*          psq  = (float*)alloc((size_t)gb * 128 * 4);
    float*          bscale = (float*)alloc(128 * 4);
    float*          bshift = (float*)alloc(128 * 4);
    // zero region: cntd, degs, fill, af
    char* zero_base = alloc((size_t)4 * N * 4);
    unsigned int* cntd = (unsigned int*)zero_base;
    unsigned int* degs = cntd + N;
    unsigned int* fill = degs + N;
    unsigned int* af   = fill + N;
    // contiguous bf16 weight region
    int o1 = D * D;                // w_proj
    int o2 = o1 + D;               // b_proj
    int o3 = o2 + D;               // bn_g
    int o4 = o3 + D;               // bn_b
    int o5 = o4 + L * D * D;       // w_in
    int o6 = o5 + L * D;           // b_in
    int o7 = o6 + L * R * D * D;   // w_rel
    int o8 = o7 + L * D * D;       // w_out
    int wt = o8 + L * D;           // b_out end
    unsigned short* wbase  = (unsigned short*)alloc((size_t)wt * 2);
    unsigned short* b_proj = wbase + o1;
    unsigned short* g_bn   = wbase + o2;
    unsigned short* b_bn   = wbase + o3;
    unsigned short* w_in   = wbase + o4;
    unsigned short* b_in   = wbase + o5;
    unsigned short* w_rel  = wbase + o6;
    unsigned short* b_out  = wbase + o8;
    unsigned short* wc     = (unsigned short*)alloc((size_t)L * R * D * D * 2);
    unsigned short* bc     = (unsigned short*)alloc((size_t)L * R * D * 2);
    unsigned short* wtg    = (unsigned short*)alloc((size_t)13 * DD * 2);
    (void)ws_size; (void)n_in; (void)out_size;

    hipMemsetAsync(zero_base, 0, (size_t)4 * N * 4, stream);

    int eb  = (E + 255) / 256;
    int nb  = (N + 255) / 256;
    int gb2 = (NI + 127) / 128;
    int nb4 = (N + 3) / 4;

    // dtype detect + normalization
    k_detect<<<1, 256, 0, stream>>>((const unsigned short*)d_in[0], flag);
    int n4 = N * D / 4;
    k_normx<<<(n4 + 255) / 256, 256, 0, stream>>>(d_in[0], xb, n4, flag);
    k_normw<<<(wt + 255) / 256, 256, 0, stream>>>(
        d_in[5], d_in[6], d_in[7], d_in[8], d_in[9], d_in[10], d_in[11], d_in[12], d_in[13],
        o1, o2, o3, o4, o5, o6, o7, o8, wt, wbase, flag);

    // CSR + degrees + dst-flags
    k_count<<<eb, 256, 0, stream>>>(ei, E, cntd, degs, idx, af, NI);
    k_scan1<<<nb, 256, 0, stream>>>(cntd, rp, bsum, N);
    k_scan2<<<1, 256, 0, stream>>>(bsum, boff, nb);
    k_scan3<<<nb, 256, 0, stream>>>(rp, boff, degs, dinv, N, E);
    k_scatter<<<eb, 256, 0, stream>>>(ei, et, E, rp, fill, pckd);

    // composed weights, then pre-transposed/swizzled GEMM weights
    gemm_compose<<<L * R, 256, 0, stream>>>(w_in, w_rel, b_in, wc, bc);
    k_prepw<<<13 * 8, 256, 0, stream>>>(wbase, wc, wtg, o4, o7);

    // proj + BN + relu
    gemm_proj<<<gb, 256, 0, stream>>>(xb, wtg, b_proj, h, N, psum, psq);
    k_bnstats<<<1, 256, 0, stream>>>(psum, psq, gb, N, g_bn, b_bn, bscale, bshift);
    int n8 = N * D / 8;
    k_bnrelu<<<(n8 + 255) / 256, 256, 0, stream>>>(h, bscale, bshift, n8);

    // layer 0 (full graph)
    gemm_fused<<<dim3(gb, 1 + R), 256, 0, stream>>>(h, wtg, b_in, bc, xl, y, N, 0);
    k_edge<<<nb4, 256, 0, stream>>>(rp, pckd, xl, y, dinv, z, N, RD, nullptr);
    gemm_fast<<<gb, 256, 0, stream>>>(z, wtg + (size_t)11 * DD, b_out, h, N, D, 0);

    // layer 1 (aggregate only dst in idx)
    gemm_fused<<<dim3(gb, 1 + R), 256, 0, stream>>>(h, wtg, b_in + D, bc + R * D, xl, y, N, 1);
    k_edge<<<nb4, 256, 0, stream>>>(rp, pckd, xl, y, dinv, z, N, RD, af);

    // final GEMM on idx-gathered rows + GeLU
    gemm_out<<<gb2, 256, 0, stream>>>(z, wtg + (size_t)12 * DD, b_out + D, d_out, NI, idx, flag);
}

// Round 5
// 413.830 us; speedup vs baseline: 1.5206x; 1.1313x over previous
//
#include <hip/hip_runtime.h>
#include <hip/hip_bf16.h>
#include <math.h>

#define D 128
#define DD (128 * 128)
#define BCAP 6600   // per-dst-bucket LDS edge capacity (avg 4096, sigma 64)

typedef __attribute__((ext_vector_type(8))) short short8;
typedef __attribute__((ext_vector_type(4))) float f32x4;

__device__ __forceinline__ float bf2f(unsigned short u) {
    union { unsigned int i; float f; } x; x.i = ((unsigned int)u) << 16; return x.f;
}
__device__ __forceinline__ unsigned short f2bf(float f) {
    unsigned int i = __float_as_uint(f);
    unsigned int r = (i + 0x7FFFu + ((i >> 16) & 1u)) >> 16;  // RNE
    return (unsigned short)r;
}

// ---------------- dtype detect ----------------
__global__ void k_detect(const unsigned short* __restrict__ x, int* __restrict__ flag) {
    __shared__ int bad;
    if (threadIdx.x == 0) bad = 0;
    __syncthreads();
    unsigned int e = (x[threadIdx.x] >> 7) & 0xFFu;
    if (e < 100u || e > 140u) atomicAdd(&bad, 1);
    __syncthreads();
    if (threadIdx.x == 0) *flag = (bad > 48) ? 1 : 0;
}

// ---------------- normalize x to bf16 (vec4) ----------------
__global__ void k_normx(const void* __restrict__ in, unsigned short* __restrict__ out,
                        int n4, const int* __restrict__ flag) {
    int i = blockIdx.x * blockDim.x + threadIdx.x;
    if (i >= n4) return;
    if (*flag) {
        float4 v = ((const float4*)in)[i];
        uint2 o;
        o.x = (unsigned int)f2bf(v.x) | ((unsigned int)f2bf(v.y) << 16);
        o.y = (unsigned int)f2bf(v.z) | ((unsigned int)f2bf(v.w) << 16);
        ((uint2*)out)[i] = o;
    } else {
        ((uint2*)out)[i] = ((const uint2*)in)[i];
    }
}

// ---------------- normalize all 9 weight tensors into one contiguous bf16 region ----------------
__global__ void k_normw(const void* s0, const void* s1, const void* s2, const void* s3,
                        const void* s4, const void* s5, const void* s6, const void* s7,
                        const void* s8,
                        int o1, int o2, int o3, int o4, int o5, int o6, int o7, int o8,
                        int total, unsigned short* __restrict__ dst, const int* __restrict__ flag) {
    int i = blockIdx.x * blockDim.x + threadIdx.x;
    if (i >= total) return;
    const void* src; int base;
    if      (i < o1) { src = s0; base = 0;  }
    else if (i < o2) { src = s1; base = o1; }
    else if (i < o3) { src = s2; base = o2; }
    else if (i < o4) { src = s3; base = o3; }
    else if (i < o5) { src = s4; base = o4; }
    else if (i < o6) { src = s5; base = o5; }
    else if (i < o7) { src = s6; base = o6; }
    else if (i < o8) { src = s7; base = o7; }
    else             { src = s8; base = o8; }
    int li = i - base;
    dst[i] = (*flag) ? f2bf(((const float*)src)[li]) : ((const unsigned short*)src)[li];
}

// ---------------- OLD gemm core (LDS transpose) — only used by gemm_compose (8 blocks) ----------------
__device__ __forceinline__ void gemm_core(
    const unsigned short* __restrict__ A, const unsigned short* __restrict__ W,
    int M, int blockRow, unsigned short* As, unsigned short* Wt, f32x4 (&acc)[2][8])
{
    int t = threadIdx.x;
    #pragma unroll
    for (int i = 0; i < 8; ++i) {
        int ch = t + i * 256;
        int row = ch >> 4;
        int kc  = ch & 15;
        int grow = blockRow + row;
        uint4 v = make_uint4(0u, 0u, 0u, 0u);
        if (grow < M) v = *((const uint4*)(A + (size_t)grow * D + kc * 8));
        int kcs = kc ^ (row & 15);
        *((uint4*)&As[row * 128 + kcs * 8]) = v;
    }
    #pragma unroll
    for (int i = 0; i < 8; ++i) {
        int ch = t + i * 256;
        int k  = ch >> 4;
        int n0 = (ch & 15) * 8;
        uint4 v = *((const uint4*)(W + k * D + n0));
        const unsigned short* pv = (const unsigned short*)&v;
        int kc = k >> 3;
        int ko = k & 7;
        #pragma unroll
        for (int j = 0; j < 8; ++j) {
            int n = n0 + j;
            Wt[n * 128 + ((kc ^ (n & 15)) * 8) + ko] = pv[j];
        }
    }
    __syncthreads();

    int wave = t >> 6;
    int lane = t & 63;
    int quad = lane >> 4;
    int l16  = lane & 15;
    int rowbase = wave * 32;

    #pragma unroll
    for (int a = 0; a < 2; ++a)
        #pragma unroll
        for (int b = 0; b < 8; ++b) acc[a][b] = (f32x4){0.f, 0.f, 0.f, 0.f};

    #pragma unroll
    for (int ks = 0; ks < 4; ++ks) {
        int chunk = ks * 4 + quad;
        short8 af[2];
        short8 bf[8];
        #pragma unroll
        for (int rt = 0; rt < 2; ++rt) {
            int r = rowbase + rt * 16 + l16;
            af[rt] = *((const short8*)&As[r * 128 + (chunk ^ (r & 15)) * 8]);
        }
        #pragma unroll
        for (int ct = 0; ct < 8; ++ct) {
            int n = ct * 16 + l16;
            bf[ct] = *((const short8*)&Wt[n * 128 + (chunk ^ (n & 15)) * 8]);
        }
        #pragma unroll
        for (int rt = 0; rt < 2; ++rt)
            #pragma unroll
            for (int ct = 0; ct < 8; ++ct)
                acc[rt][ct] = __builtin_amdgcn_mfma_f32_16x16x32_bf16(af[rt], bf[ct], acc[rt][ct], 0, 0, 0);
    }
}

__device__ __forceinline__ void store_c(
    f32x4 (&acc)[2][8], const unsigned short* __restrict__ bias,
    unsigned short* __restrict__ C, int M, int blockRow, int ldc, int coloff)
{
    int t = threadIdx.x;
    int wave = t >> 6;
    int lane = t & 63;
    int quad = lane >> 4;
    int l16  = lane & 15;
    int rowbase = wave * 32;
    #pragma unroll
    for (int rt = 0; rt < 2; ++rt) {
        #pragma unroll
        for (int ct = 0; ct < 8; ++ct) {
            int col = ct * 16 + l16;
            float bv = bias ? bf2f(bias[col]) : 0.f;
            #pragma unroll
            for (int r = 0; r < 4; ++r) {
                int grow = blockRow + rowbase + rt * 16 + quad * 4 + r;
                if (grow < M) {
                    float v = acc[rt][ct][r] + bv;
                    C[(size_t)grow * ldc + coloff + col] = f2bf(v);
                }
            }
        }
    }
}

// ---------------- weight composition: Wc[b] = win_w[l] @ wrel[b], bc[b] = win_b[l] @ wrel[b] ----------------
__global__ __launch_bounds__(256) void gemm_compose(
    const unsigned short* __restrict__ w_in, const unsigned short* __restrict__ wrel,
    const unsigned short* __restrict__ b_in, unsigned short* __restrict__ wc,
    unsigned short* __restrict__ bc)
{
    __shared__ unsigned short As[DD];
    __shared__ unsigned short Wt[DD];
    f32x4 acc[2][8];
    int b = blockIdx.x;          // l*4 + r
    int l = b >> 2;
    const unsigned short* A = w_in + (size_t)l * DD;
    const unsigned short* W = wrel + (size_t)b * DD;
    gemm_core(A, W, 128, 0, As, Wt, acc);
    store_c(acc, nullptr, wc + (size_t)b * DD, 128, 0, D, 0);
    int t = threadIdx.x;
    if (t < 128) {
        float s = 0.f;
        for (int k = 0; k < 128; ++k)
            s += bf2f(b_in[l * D + k]) * bf2f(W[k * D + t]);
        bc[b * D + t] = f2bf(s);
    }
}

// ---------------- pre-transpose + swizzle 13 weight mats ----------------
__global__ __launch_bounds__(256) void k_prepw(
    const unsigned short* __restrict__ wbase, const unsigned short* __restrict__ wc,
    unsigned short* __restrict__ wtg, int o4, int o7)
{
    int m = blockIdx.x >> 3;
    int sub = blockIdx.x & 7;
    const unsigned short* src;
    if (m == 0)       src = wbase;                         // w_proj
    else if (m <= 2)  src = wbase + o4 + (m - 1) * DD;     // w_in[l]
    else if (m <= 10) src = wc + (size_t)(m - 3) * DD;     // composed wc[l*4+r]
    else              src = wbase + o7 + (m - 11) * DD;    // w_out[l]
    int c = sub * 256 + threadIdx.x;   // 0..2047
    int n = c >> 4;
    int kc = c & 15;
    unsigned short tmp[8];
    #pragma unroll
    for (int ko = 0; ko < 8; ++ko) tmp[ko] = src[(kc * 8 + ko) * 128 + n];
    *((uint4*)(wtg + (size_t)m * DD + n * 128 + ((kc ^ (n & 15)) * 8))) = *(uint4*)tmp;
}

// ---------------- FAST gemm core ----------------
__device__ __forceinline__ void gemm_core_fast(
    const unsigned short* __restrict__ A,
    const unsigned short* __restrict__ Wt_g,
    int M, int blockRow, const int* __restrict__ rowmap,
    unsigned short* Wt, f32x4 (&acc)[2][8])
{
    int t = threadIdx.x;
    #pragma unroll
    for (int i = 0; i < 8; ++i)
        ((uint4*)Wt)[t + i * 256] = ((const uint4*)Wt_g)[t + i * 256];

    int wave = t >> 6, lane = t & 63, quad = lane >> 4, l16 = lane & 15;
    int rowbase = blockRow + wave * 32;
    int r0 = min(rowbase + l16, M - 1);
    int r1 = min(rowbase + 16 + l16, M - 1);
    if (rowmap) { r0 = rowmap[r0]; r1 = rowmap[r1]; }
    const unsigned short* a0 = A + (size_t)r0 * D;
    const unsigned short* a1 = A + (size_t)r1 * D;
    short8 af[2][4];
    #pragma unroll
    for (int ks = 0; ks < 4; ++ks) {
        int chunk = ks * 4 + quad;
        af[0][ks] = *((const short8*)(a0 + chunk * 8));
        af[1][ks] = *((const short8*)(a1 + chunk * 8));
    }
    #pragma unroll
    for (int a = 0; a < 2; ++a)
        #pragma unroll
        for (int b = 0; b < 8; ++b) acc[a][b] = (f32x4){0.f, 0.f, 0.f, 0.f};
    __syncthreads();
    #pragma unroll
    for (int ks = 0; ks < 4; ++ks) {
        int chunk = ks * 4 + quad;
        short8 bf[8];
        #pragma unroll
        for (int ct = 0; ct < 8; ++ct)
            bf[ct] = *((const short8*)&Wt[(ct * 16 + l16) * 128 + ((chunk ^ l16) * 8)]);
        #pragma unroll
        for (int rt = 0; rt < 2; ++rt)
            #pragma unroll
            for (int ct = 0; ct < 8; ++ct)
                acc[rt][ct] = __builtin_amdgcn_mfma_f32_16x16x32_bf16(af[rt][ks], bf[ct], acc[rt][ct], 0, 0, 0);
    }
}

// ---------------- plain fast GEMM ----------------
__global__ __launch_bounds__(256) void gemm_fast(
    const unsigned short* __restrict__ A, const unsigned short* __restrict__ Wt_g,
    const unsigned short* __restrict__ bias, unsigned short* __restrict__ C,
    int M, int ldc, int coloff)
{
    __shared__ unsigned short Wt[DD];
    f32x4 acc[2][8];
    gemm_core_fast(A, Wt_g, M, blockIdx.x * 128, nullptr, Wt, acc);
    store_c(acc, bias, C, M, blockIdx.x * 128, ldc, coloff);
}

// ---------------- proj GEMM + per-block BN partial stats ----------------
__global__ __launch_bounds__(256) void gemm_proj(
    const unsigned short* __restrict__ A, const unsigned short* __restrict__ Wt_g,
    const unsigned short* __restrict__ bias, unsigned short* __restrict__ C,
    int M, float* __restrict__ psum, float* __restrict__ psq)
{
    __shared__ unsigned short Wt[DD];
    __shared__ float smS[4][128], smQ[4][128];
    f32x4 acc[2][8];
    int blockRow = blockIdx.x * 128;
    gemm_core_fast(A, Wt_g, M, blockRow, nullptr, Wt, acc);

    int t = threadIdx.x;
    int wave = t >> 6, lane = t & 63, quad = lane >> 4, l16 = lane & 15;
    int rowbase = wave * 32;
    #pragma unroll
    for (int ct = 0; ct < 8; ++ct) {
        int col = ct * 16 + l16;
        float bv = bf2f(bias[col]);
        float ps = 0.f, pq = 0.f;
        #pragma unroll
        for (int rt = 0; rt < 2; ++rt) {
            #pragma unroll
            for (int r = 0; r < 4; ++r) {
                int grow = blockRow + rowbase + rt * 16 + quad * 4 + r;
                if (grow < M) {
                    float v = acc[rt][ct][r] + bv;
                    C[(size_t)grow * D + col] = f2bf(v);
                    ps += v; pq += v * v;
                }
            }
        }
        ps += __shfl_xor(ps, 16, 64); ps += __shfl_xor(ps, 32, 64);
        pq += __shfl_xor(pq, 16, 64); pq += __shfl_xor(pq, 32, 64);
        if (quad == 0) { smS[wave][col] = ps; smQ[wave][col] = pq; }
    }
    __syncthreads();
    if (t < 128) {
        float s = smS[0][t] + smS[1][t] + smS[2][t] + smS[3][t];
        float q = smQ[0][t] + smQ[1][t] + smQ[2][t] + smQ[3][t];
        psum[blockIdx.x * 128 + t] = s;
        psq[blockIdx.x * 128 + t] = q;
    }
}

// ---------------- fused per-layer GEMM: slice 0 -> xl; slices 1..4 -> y_r ----------------
__global__ __launch_bounds__(256) void gemm_fused(
    const unsigned short* __restrict__ h, const unsigned short* __restrict__ wtg,
    const unsigned short* __restrict__ b_in_l, const unsigned short* __restrict__ bc_l,
    unsigned short* __restrict__ xl, unsigned short* __restrict__ y, int M, int l)
{
    __shared__ unsigned short Wt[DD];
    f32x4 acc[2][8];
    int slice = blockIdx.y;
    int m = (slice == 0) ? (1 + l) : (3 + l * 4 + slice - 1);
    const unsigned short* bias = (slice == 0) ? b_in_l : bc_l + (slice - 1) * D;
    unsigned short* C = (slice == 0) ? xl : y;
    int ldc    = (slice == 0) ? D : 4 * D;
    int coloff = (slice == 0) ? 0 : (slice - 1) * D;
    gemm_core_fast(h, wtg + (size_t)m * DD, M, blockIdx.x * 128, nullptr, Wt, acc);
    store_c(acc, bias, C, M, blockIdx.x * 128, ldc, coloff);
}

// ---------------- final GEMM: A rows gathered via idx, exact GeLU epilogue ----------------
__global__ __launch_bounds__(256) void gemm_out(
    const unsigned short* __restrict__ z, const unsigned short* __restrict__ Wt_g,
    const unsigned short* __restrict__ bias, void* __restrict__ out,
    int M, const int* __restrict__ idx, const int* __restrict__ flag)
{
    __shared__ unsigned short Wt[DD];
    f32x4 acc[2][8];
    int blockRow = blockIdx.x * 128;
    gemm_core_fast(z, Wt_g, M, blockRow, idx, Wt, acc);
    int fl = *flag;
    int t = threadIdx.x;
    int wave = t >> 6, lane = t & 63, quad = lane >> 4, l16 = lane & 15;
    int rowbase = wave * 32;
    #pragma unroll
    for (int rt = 0; rt < 2; ++rt) {
        #pragma unroll
        for (int ct = 0; ct < 8; ++ct) {
            int col = ct * 16 + l16;
            float bv = bf2f(bias[col]);
            #pragma unroll
            for (int r = 0; r < 4; ++r) {
                int grow = blockRow + rowbase + rt * 16 + quad * 4 + r;
                if (grow < M) {
                    float v = acc[rt][ct][r] + bv;
                    float gl = 0.5f * v * (1.f + erff(v * 0.70710678118654752f));
                    size_t o = (size_t)grow * D + col;
                    if (fl) ((float*)out)[o] = gl;
                    else    ((unsigned short*)out)[o] = f2bf(gl);
                }
            }
        }
    }
}

// ================= atomic-free CSR build via single-digit bucket sort =================
// bucket = node >> 8 (max 256 buckets for N < 65536)

// per-block LDS histograms over dst-buckets and src-buckets; also seed af flags
__global__ __launch_bounds__(256) void k_hista(
    const int* __restrict__ ei, int E,
    unsigned int* __restrict__ part_dst, unsigned int* __restrict__ part_src,
    const int* __restrict__ idx, unsigned int* __restrict__ af, int NI)
{
    __shared__ unsigned int hd[256], hs[256];
    int b = blockIdx.x, t = threadIdx.x;
    hd[t] = 0u; hs[t] = 0u;
    int gid = b * 256 + t;
    if (gid < NI) af[idx[gid]] = 1u;
    __syncthreads();
    int base = b * 2048;
    #pragma unroll
    for (int i = 0; i < 8; ++i) {
        int e = base + t + i * 256;
        if (e < E) {
            atomicAdd(&hd[((unsigned int)ei[e]) >> 8], 1u);
            atomicAdd(&hs[((unsigned int)ei[E + e]) >> 8], 1u);
        }
    }
    __syncthreads();
    part_dst[b * 256 + t] = hd[t];
    part_src[b * 256 + t] = hs[t];
}

// scan per-bucket partials over blocks (grid.x=256 buckets, grid.y=2 arrays); BA <= 512
__global__ void k_scanpart(unsigned int* __restrict__ part_d, unsigned int* __restrict__ part_s,
                           unsigned int* __restrict__ btot_d, unsigned int* __restrict__ btot_s,
                           int BA)
{
    __shared__ unsigned int arr[512];
    unsigned int* part = blockIdx.y ? part_s : part_d;
    unsigned int* btot = blockIdx.y ? btot_s : btot_d;
    int bucket = blockIdx.x, t = threadIdx.x;
    unsigned int v0 = (t < BA) ? part[t * 256 + bucket] : 0u;
    unsigned int v1 = (t + 256 < BA) ? part[(t + 256) * 256 + bucket] : 0u;
    arr[t] = v0; arr[t + 256] = v1;
    __syncthreads();
    for (int off = 1; off < 512; off <<= 1) {
        unsigned int a = arr[t], b2 = arr[t + 256];
        unsigned int pa = (t >= off) ? arr[t - off] : 0u;
        unsigned int pb = (t + 256 >= off) ? arr[t + 256 - off] : 0u;
        __syncthreads();
        arr[t] = a + pa; arr[t + 256] = b2 + pb;
        __syncthreads();
    }
    if (t < BA) part[t * 256 + bucket] = arr[t] - v0;
    if (t + 256 < BA) part[(t + 256) * 256 + bucket] = arr[t + 256] - v1;
    if (t == 0) btot[bucket] = arr[511];
}

// exclusive scan of 256 bucket totals -> bucket bases (both arrays, one block)
__global__ void k_scanbase(const unsigned int* __restrict__ btot_d, const unsigned int* __restrict__ btot_s,
                           unsigned int* __restrict__ bbase_d, unsigned int* __restrict__ bbase_s)
{
    __shared__ unsigned int a1[256], a2[256];
    int t = threadIdx.x;
    unsigned int vd = btot_d[t], vs = btot_s[t];
    a1[t] = vd; a2[t] = vs;
    __syncthreads();
    for (int off = 1; off < 256; off <<= 1) {
        unsigned int x = a1[t], y = a2[t];
        unsigned int px = (t >= off) ? a1[t - off] : 0u;
        unsigned int py = (t >= off) ? a2[t - off] : 0u;
        __syncthreads();
        a1[t] = x + px; a2[t] = y + py;
        __syncthreads();
    }
    bbase_d[t] = a1[t] - vd;
    bbase_s[t] = a2[t] - vs;
    if (t == 255) { bbase_d[256] = a1[255]; bbase_s[256] = a2[255]; }
}

// scatter edges into dst-bucket regions (uint2 {dst, src|type<<16}) and src values into src-buckets
__global__ __launch_bounds__(256) void k_bscatter(
    const int* __restrict__ ei, const int* __restrict__ et, int E,
    const unsigned int* __restrict__ part_dst, const unsigned int* __restrict__ part_src,
    const unsigned int* __restrict__ bbase_d, const unsigned int* __restrict__ bbase_s,
    uint2* __restrict__ ebuck, unsigned short* __restrict__ sbuck)
{
    __shared__ unsigned int cd[256], cs[256];
    int b = blockIdx.x, t = threadIdx.x;
    cd[t] = part_dst[b * 256 + t] + bbase_d[t];
    cs[t] = part_src[b * 256 + t] + bbase_s[t];
    __syncthreads();
    int base = b * 2048;
    #pragma unroll
    for (int i = 0; i < 8; ++i) {
        int e = base + t + i * 256;
        if (e < E) {
            unsigned int d = (unsigned int)ei[e];
            unsigned int s = (unsigned int)ei[E + e];
            unsigned int tt = (unsigned int)et[e];
            unsigned int pd = atomicAdd(&cd[d >> 8], 1u);
            ebuck[pd] = make_uint2(d, s | (tt << 16));
            unsigned int ps = atomicAdd(&cs[s >> 8], 1u);
            sbuck[ps] = (unsigned short)s;
        }
    }
}

// per-dst-bucket 256-bin counting sort in LDS -> rp + dst-grouped pckd
__global__ __launch_bounds__(256) void k_bucket_dst(
    const unsigned int* __restrict__ bbase, const uint2* __restrict__ ebuck,
    unsigned int* __restrict__ rp, unsigned int* __restrict__ pckd, int N)
{
    __shared__ uint2 ebuf[BCAP];
    __shared__ unsigned int bins[256], scn[256], cur[256];
    int b = blockIdx.x, t = threadIdx.x;
    unsigned int beg = bbase[b], end = bbase[b + 1];
    unsigned int cnt = end - beg;
    bins[t] = 0u;
    __syncthreads();
    bool fit = cnt <= (unsigned int)BCAP;
    if (fit) {
        for (unsigned int i = t; i < cnt; i += 256) {
            uint2 v = ebuck[beg + i];
            ebuf[i] = v;
            atomicAdd(&bins[v.x & 255u], 1u);
        }
    } else {
        for (unsigned int i = t; i < cnt; i += 256)
            atomicAdd(&bins[ebuck[beg + i].x & 255u], 1u);
    }
    __syncthreads();
    scn[t] = bins[t];
    __syncthreads();
    for (int off = 1; off < 256; off <<= 1) {
        unsigned int v = scn[t];
        unsigned int a = (t >= off) ? scn[t - off] : 0u;
        __syncthreads();
        scn[t] = v + a;
        __syncthreads();
    }
    unsigned int ex = scn[t] - bins[t];
    int n = (b << 8) + t;
    if (n <= N) rp[n] = beg + ex;
    cur[t] = beg + ex;
    __syncthreads();
    if (fit) {
        for (unsigned int i = t; i < cnt; i += 256) {
            uint2 v = ebuf[i];
            unsigned int pos = atomicAdd(&cur[v.x & 255u], 1u);
            pckd[pos] = v.y;
        }
    } else {
        for (unsigned int i = t; i < cnt; i += 256) {
            uint2 v = ebuck[beg + i];
            unsigned int pos = atomicAdd(&cur[v.x & 255u], 1u);
            pckd[pos] = v.y;
        }
    }
}

// per-src-bucket 256-bin histogram -> dinv
__global__ __launch_bounds__(256) void k_bucket_src(
    const unsigned int* __restrict__ bbase, const unsigned short* __restrict__ sbuck,
    float* __restrict__ dinv, int N)
{
    __shared__ unsigned int bins[256];
    int b = blockIdx.x, t = threadIdx.x;
    unsigned int beg = bbase[b], end = bbase[b + 1];
    bins[t] = 0u;
    __syncthreads();
    for (unsigned int i = beg + t; i < end; i += 256)
        atomicAdd(&bins[sbuck[i] & 255u], 1u);
    __syncthreads();
    int n = (b << 8) + t;
    if (n < N) {
        unsigned int dg = bins[t];
        dinv[n] = dg ? rsqrtf((float)dg) : 0.f;
    }
}

// ---------------- BN stats reduce (1 block) ----------------
__global__ void k_bnstats(const float* __restrict__ psum, const float* __restrict__ psq,
                          int nb, int N, const unsigned short* __restrict__ g,
                          const unsigned short* __restrict__ b,
                          float* __restrict__ scale, float* __restrict__ shift) {
    int col = threadIdx.x & 127, h = threadIdx.x >> 7;
    float s = 0.f, q = 0.f;
    for (int i = h; i < nb; i += 2) { s += psum[i * 128 + col]; q += psq[i * 128 + col]; }
    __shared__ float sS[256], sQ[256];
    sS[threadIdx.x] = s; sQ[threadIdx.x] = q;
    __syncthreads();
    if (h == 0) {
        s = sS[col] + sS[col + 128];
        q = sQ[col] + sQ[col + 128];
        float inv = 1.f / (float)N;
        float mean = s * inv;
        float var = fmaxf(q * inv - mean * mean, 0.f);
        float sc = rsqrtf(var + 1e-5f) * bf2f(g[col]);
        scale[col] = sc;
        shift[col] = bf2f(b[col]) - mean * sc;
    }
}

// ---------------- BN apply + relu (vec 8 shorts/thread) ----------------
__global__ void k_bnrelu(unsigned short* __restrict__ h, const float* __restrict__ scale,
                         const float* __restrict__ shift, int n8) {
    int i = blockIdx.x * blockDim.x + threadIdx.x;
    if (i >= n8) return;
    int cb = (i & 15) * 8;
    uint4 v = ((uint4*)h)[i];
    unsigned int* w = (unsigned int*)&v;
    #pragma unroll
    for (int j = 0; j < 4; ++j) {
        int c = cb + j * 2;
        float v0 = __uint_as_float(w[j] << 16);
        float v1 = __uint_as_float(w[j] & 0xFFFF0000u);
        v0 = fmaxf(fmaf(v0, scale[c], shift[c]), 0.f);
        v1 = fmaxf(fmaf(v1, scale[c + 1], shift[c + 1]), 0.f);
        w[j] = (unsigned int)f2bf(v0) | ((unsigned int)f2bf(v1) << 16);
    }
    ((uint4*)h)[i] = v;
}

// ---------------- edge aggregation: 1 wave/node, 4 edges concurrent, 8 ch/lane ----------------
__global__ __launch_bounds__(256) void k_edge(
    const unsigned int* __restrict__ rp, const unsigned int* __restrict__ packed,
    const unsigned short* __restrict__ xl, const unsigned short* __restrict__ y,
    const float* __restrict__ dinv, unsigned short* __restrict__ z, int N, int RD,
    const unsigned int* __restrict__ af)
{
    int lane = threadIdx.x & 63;
    int node = blockIdx.x * 4 + (threadIdx.x >> 6);
    node = __builtin_amdgcn_readfirstlane(node);
    if (node >= N) return;
    if (af && af[node] == 0u) return;
    unsigned int beg = rp[node], end = rp[node + 1];
    int eg = lane >> 4;
    int cb = (lane & 15) * 8;
    float g[8], dd[8], ss[8];
    #pragma unroll
    for (int j = 0; j < 8; ++j) { g[j] = 0.f; dd[j] = 0.f; ss[j] = 0.f; }

    for (unsigned int e0 = beg; e0 < end; e0 += 4) {
        unsigned int e = e0 + (unsigned int)eg;
        bool valid = e < end;
        unsigned int p = packed[valid ? e : beg];
        unsigned int s = p & 0xFFFFu;
        unsigned int tt = p >> 16;
        float ds = valid ? dinv[s] : 0.f;
        uint4 xv = *((const uint4*)(xl + (size_t)s * D + cb));
        uint4 yv = *((const uint4*)(y + (size_t)s * RD + tt * D + cb));
        const unsigned int* xw = (const unsigned int*)&xv;
        const unsigned int* yw = (const unsigned int*)&yv;
        #pragma unroll
        for (int w = 0; w < 4; ++w) {
            float x0 = __uint_as_float(xw[w] << 16);
            float x1 = __uint_as_float(xw[w] & 0xFFFF0000u);
            float v0 = __uint_as_float(yw[w] << 16);
            float v1 = __uint_as_float(yw[w] & 0xFFFF0000u);
            int j0 = w * 2, j1 = w * 2 + 1;
            g[j0] = fmaf(x0, ds, g[j0]);
            g[j1] = fmaf(x1, ds, g[j1]);
            float e0f = __expf(v0); if (!valid) e0f = 0.f;
            float e1f = __expf(v1); if (!valid) e1f = 0.f;
            dd[j0] += e0f; dd[j1] += e1f;
            ss[j0] = fmaf(v0, e0f, ss[j0]);
            ss[j1] = fmaf(v1, e1f, ss[j1]);
        }
    }

    #pragma unroll
    for (int j = 0; j < 8; ++j) {
        g[j]  += __shfl_xor(g[j], 16, 64);  g[j]  += __shfl_xor(g[j], 32, 64);
        dd[j] += __shfl_xor(dd[j], 16, 64); dd[j] += __shfl_xor(dd[j], 32, 64);
        ss[j] += __shfl_xor(ss[j], 16, 64); ss[j] += __shfl_xor(ss[j], 32, 64);
    }
    if (eg == 0) {
        float dn = dinv[node];
        unsigned int o[4];
        #pragma unroll
        for (int w = 0; w < 4; ++w) {
            int j0 = w * 2, j1 = w * 2 + 1;
            float m0 = (dd[j0] > 0.f) ? ss[j0] / dd[j0] : 0.f;
            float m1 = (dd[j1] > 0.f) ? ss[j1] / dd[j1] : 0.f;
            float z0 = fmaf(g[j0], dn, 0.1f * fmaxf(m0, 0.f));
            float z1 = fmaf(g[j1], dn, 0.1f * fmaxf(m1, 0.f));
            o[w] = (unsigned int)f2bf(z0) | ((unsigned int)f2bf(z1) << 16);
        }
        *((uint4*)(z + (size_t)node * D + cb)) = *(uint4*)o;
    }
}

extern "C" void kernel_launch(void* const* d_in, const int* in_sizes, int n_in,
                              void* d_out, int out_size, void* d_ws, size_t ws_size,
                              hipStream_t stream)
{
    const int* ei  = (const int*)d_in[1];
    const int* idx = (const int*)d_in[2];
    const int* et  = (const int*)d_in[3];

    int N  = in_sizes[0] / D;            // 48758
    int E  = in_sizes[1] / 2;            // 780000
    int NI = in_sizes[2];                // 10000
    int L  = in_sizes[9] / (D * D);      // 2
    int R  = in_sizes[11] / (L * D * D); // 4
    int RD = R * D;

    int NB = (N + 255) >> 8;             // 191 dst/src buckets
    int BA = (E + 2047) / 2048;          // 381 scatter blocks

    char* ws = (char*)d_ws;
    size_t off = 0;
    auto alloc = [&](size_t bytes) -> char* {
        char* p = ws + off;
        off += (bytes + 255) & ~(size_t)255;
        return p;
    };
    unsigned short* h    = (unsigned short*)alloc((size_t)N * D * 2);
    unsigned short* xl   = (unsigned short*)alloc((size_t)N * D * 2);
    unsigned short* y    = (unsigned short*)alloc((size_t)N * RD * 2);
    unsigned short* z    = (unsigned short*)alloc((size_t)N * D * 2);
    unsigned short* xb   = (unsigned short*)alloc((size_t)N * D * 2);
    float*          dinv = (float*)alloc((size_t)N * 4);
    unsigned int*   rp   = (unsigned int*)alloc((size_t)(N + 1) * 4);
    int*            flag = (int*)alloc(256);
    unsigned int*   pckd = (unsigned int*)alloc((size_t)E * 4);
    int gb  = (N + 127) / 128;
    float*          psum = (float*)alloc((size_t)gb * 128 * 4);
    float*          psq  = (float*)alloc((size_t)gb * 128 * 4);
    float*          bscale = (float*)alloc(128 * 4);
    float*          bshift = (float*)alloc(128 * 4);
    // bucket-sort scratch
    unsigned int*   part_dst = (unsigned int*)alloc((size_t)BA * 256 * 4);
    unsigned int*   part_src = (unsigned int*)alloc((size_t)BA * 256 * 4);
    unsigned int*   btot_d   = (unsigned int*)alloc(256 * 4);
    unsigned int*   btot_s   = (unsigned int*)alloc(256 * 4);
    unsigned int*   bbase_d  = (unsigned int*)alloc(257 * 4);
    unsigned int*   bbase_s  = (unsigned int*)alloc(257 * 4);
    // aliases into regions that are dead during graph prep
    uint2*          ebuck = (uint2*)y;           // E*8 <= N*RD*2
    unsigned short* sbuck = (unsigned short*)z;  // E*2 <= N*D*2
    // zero region: af only
    unsigned int*   af = (unsigned int*)alloc((size_t)N * 4);
    // contiguous bf16 weight region
    int o1 = D * D;                // w_proj
    int o2 = o1 + D;               // b_proj
    int o3 = o2 + D;               // bn_g
    int o4 = o3 + D;               // bn_b
    int o5 = o4 + L * D * D;       // w_in
    int o6 = o5 + L * D;           // b_in
    int o7 = o6 + L * R * D * D;   // w_rel
    int o8 = o7 + L * D * D;       // w_out
    int wt = o8 + L * D;           // b_out end
    unsigned short* wbase  = (unsigned short*)alloc((size_t)wt * 2);
    unsigned short* b_proj = wbase + o1;
    unsigned short* g_bn   = wbase + o2;
    unsigned short* b_bn   = wbase + o3;
    unsigned short* w_in   = wbase + o4;
    unsigned short* b_in   = wbase + o5;
    unsigned short* w_rel  = wbase + o6;
    unsigned short* b_out  = wbase + o8;
    unsigned short* wc     = (unsigned short*)alloc((size_t)L * R * D * D * 2);
    unsigned short* bc     = (unsigned short*)alloc((size_t)L * R * D * 2);
    unsigned short* wtg    = (unsigned short*)alloc((size_t)13 * DD * 2);
    (void)ws_size; (void)n_in; (void)out_size;

    hipMemsetAsync(af, 0, (size_t)N * 4, stream);

    int gb2 = (NI + 127) / 128;
    int nb4 = (N + 3) / 4;

    // dtype detect + normalization
    k_detect<<<1, 256, 0, stream>>>((const unsigned short*)d_in[0], flag);
    int n4 = N * D / 4;
    k_normx<<<(n4 + 255) / 256, 256, 0, stream>>>(d_in[0], xb, n4, flag);
    k_normw<<<(wt + 255) / 256, 256, 0, stream>>>(
        d_in[5], d_in[6], d_in[7], d_in[8], d_in[9], d_in[10], d_in[11], d_in[12], d_in[13],
        o1, o2, o3, o4, o5, o6, o7, o8, wt, wbase, flag);

    // atomic-free CSR build
    k_hista<<<BA, 256, 0, stream>>>(ei, E, part_dst, part_src, idx, af, NI);
    k_scanpart<<<dim3(256, 2), 256, 0, stream>>>(part_dst, part_src, btot_d, btot_s, BA);
    k_scanbase<<<1, 256, 0, stream>>>(btot_d, btot_s, bbase_d, bbase_s);
    k_bscatter<<<BA, 256, 0, stream>>>(ei, et, E, part_dst, part_src, bbase_d, bbase_s, ebuck, sbuck);
    k_bucket_dst<<<NB, 256, 0, stream>>>(bbase_d, ebuck, rp, pckd, N);
    k_bucket_src<<<NB, 256, 0, stream>>>(bbase_s, sbuck, dinv, N);

    // composed weights, then pre-transposed/swizzled GEMM weights
    gemm_compose<<<L * R, 256, 0, stream>>>(w_in, w_rel, b_in, wc, bc);
    k_prepw<<<13 * 8, 256, 0, stream>>>(wbase, wc, wtg, o4, o7);

    // proj + BN + relu
    gemm_proj<<<gb, 256, 0, stream>>>(xb, wtg, b_proj, h, N, psum, psq);
    k_bnstats<<<1, 256, 0, stream>>>(psum, psq, gb, N, g_bn, b_bn, bscale, bshift);
    int n8 = N * D / 8;
    k_bnrelu<<<(n8 + 255) / 256, 256, 0, stream>>>(h, bscale, bshift, n8);

    // layer 0 (full graph)
    gemm_fused<<<dim3(gb, 1 + R), 256, 0, stream>>>(h, wtg, b_in, bc, xl, y, N, 0);
    k_edge<<<nb4, 256, 0, stream>>>(rp, pckd, xl, y, dinv, z, N, RD, nullptr);
    gemm_fast<<<gb, 256, 0, stream>>>(z, wtg + (size_t)11 * DD, b_out, h, N, D, 0);

    // layer 1 (aggregate only dst in idx)
    gemm_fused<<<dim3(gb, 1 + R), 256, 0, stream>>>(h, wtg, b_in + D, bc + R * D, xl, y, N, 1);
    k_edge<<<nb4, 256, 0, stream>>>(rp, pckd, xl, y, dinv, z, N, RD, af);

    // final GEMM on idx-gathered rows + GeLU
    gemm_out<<<gb2, 256, 0, stream>>>(z, wtg + (size_t)12 * DD, b_out + D, d_out, NI, idx, flag);
}

// Round 6
// 382.753 us; speedup vs baseline: 1.6441x; 1.0812x over previous
//
#include <hip/hip_runtime.h>
#include <hip/hip_bf16.h>
#include <math.h>

#define D 128
#define DD (128 * 128)
#define BCAP 6600   // per-dst-bucket LDS edge capacity (avg 4096, sigma ~64)

typedef __attribute__((ext_vector_type(8))) short short8;
typedef __attribute__((ext_vector_type(4))) float f32x4;

__device__ __forceinline__ float bf2f(unsigned short u) {
    union { unsigned int i; float f; } x; x.i = ((unsigned int)u) << 16; return x.f;
}
__device__ __forceinline__ unsigned short f2bf(float f) {
    unsigned int i = __float_as_uint(f);
    unsigned int r = (i + 0x7FFFu + ((i >> 16) & 1u)) >> 16;  // RNE
    return (unsigned short)r;
}

// inline dtype vote: fp32 read as shorts -> ~50% random exponent fields. 256-thread blocks.
__device__ __forceinline__ int vote_flag(const unsigned short* __restrict__ x) {
    __shared__ int bad_s;
    if (threadIdx.x == 0) bad_s = 0;
    __syncthreads();
    unsigned int e = (x[threadIdx.x] >> 7) & 0xFFu;
    unsigned long long b = __ballot(e < 100u || e > 140u);
    if ((threadIdx.x & 63) == 0) atomicAdd(&bad_s, __popcll(b));
    __syncthreads();
    return bad_s > 48 ? 1 : 0;
}

// ---------------- normalize x (vec4) + all 9 weight tensors, one kernel ----------------
__global__ __launch_bounds__(256) void k_normall(
    const void* __restrict__ xin, unsigned short* __restrict__ xb, int n4, int nbx,
    const void* s0, const void* s1, const void* s2, const void* s3,
    const void* s4, const void* s5, const void* s6, const void* s7, const void* s8,
    int o1, int o2, int o3, int o4, int o5, int o6, int o7, int o8,
    int total, unsigned short* __restrict__ wdst)
{
    int fl = vote_flag((const unsigned short*)xin);
    if (blockIdx.x < nbx) {
        int i = blockIdx.x * 256 + threadIdx.x;
        if (i >= n4) return;
        if (fl) {
            float4 v = ((const float4*)xin)[i];
            uint2 o;
            o.x = (unsigned int)f2bf(v.x) | ((unsigned int)f2bf(v.y) << 16);
            o.y = (unsigned int)f2bf(v.z) | ((unsigned int)f2bf(v.w) << 16);
            ((uint2*)xb)[i] = o;
        } else {
            ((uint2*)xb)[i] = ((const uint2*)xin)[i];
        }
    } else {
        int i = (blockIdx.x - nbx) * 256 + threadIdx.x;
        if (i >= total) return;
        const void* src; int base;
        if      (i < o1) { src = s0; base = 0;  }
        else if (i < o2) { src = s1; base = o1; }
        else if (i < o3) { src = s2; base = o2; }
        else if (i < o4) { src = s3; base = o3; }
        else if (i < o5) { src = s4; base = o4; }
        else if (i < o6) { src = s5; base = o5; }
        else if (i < o7) { src = s6; base = o6; }
        else if (i < o8) { src = s7; base = o7; }
        else             { src = s8; base = o8; }
        int li = i - base;
        wdst[i] = fl ? f2bf(((const float*)src)[li]) : ((const unsigned short*)src)[li];
    }
}

// ---------------- OLD gemm core (LDS transpose) — only used by gemm_compose (8 blocks) ----------------
__device__ __forceinline__ void gemm_core(
    const unsigned short* __restrict__ A, const unsigned short* __restrict__ W,
    int M, int blockRow, unsigned short* As, unsigned short* Wt, f32x4 (&acc)[2][8])
{
    int t = threadIdx.x;
    #pragma unroll
    for (int i = 0; i < 8; ++i) {
        int ch = t + i * 256;
        int row = ch >> 4;
        int kc  = ch & 15;
        int grow = blockRow + row;
        uint4 v = make_uint4(0u, 0u, 0u, 0u);
        if (grow < M) v = *((const uint4*)(A + (size_t)grow * D + kc * 8));
        int kcs = kc ^ (row & 15);
        *((uint4*)&As[row * 128 + kcs * 8]) = v;
    }
    #pragma unroll
    for (int i = 0; i < 8; ++i) {
        int ch = t + i * 256;
        int k  = ch >> 4;
        int n0 = (ch & 15) * 8;
        uint4 v = *((const uint4*)(W + k * D + n0));
        const unsigned short* pv = (const unsigned short*)&v;
        int kc = k >> 3;
        int ko = k & 7;
        #pragma unroll
        for (int j = 0; j < 8; ++j) {
            int n = n0 + j;
            Wt[n * 128 + ((kc ^ (n & 15)) * 8) + ko] = pv[j];
        }
    }
    __syncthreads();

    int wave = t >> 6, lane = t & 63, quad = lane >> 4, l16 = lane & 15;
    int rowbase = wave * 32;

    #pragma unroll
    for (int a = 0; a < 2; ++a)
        #pragma unroll
        for (int b = 0; b < 8; ++b) acc[a][b] = (f32x4){0.f, 0.f, 0.f, 0.f};

    #pragma unroll
    for (int ks = 0; ks < 4; ++ks) {
        int chunk = ks * 4 + quad;
        short8 af[2];
        short8 bf[8];
        #pragma unroll
        for (int rt = 0; rt < 2; ++rt) {
            int r = rowbase + rt * 16 + l16;
            af[rt] = *((const short8*)&As[r * 128 + (chunk ^ (r & 15)) * 8]);
        }
        #pragma unroll
        for (int ct = 0; ct < 8; ++ct) {
            int n = ct * 16 + l16;
            bf[ct] = *((const short8*)&Wt[n * 128 + (chunk ^ (n & 15)) * 8]);
        }
        #pragma unroll
        for (int rt = 0; rt < 2; ++rt)
            #pragma unroll
            for (int ct = 0; ct < 8; ++ct)
                acc[rt][ct] = __builtin_amdgcn_mfma_f32_16x16x32_bf16(af[rt], bf[ct], acc[rt][ct], 0, 0, 0);
    }
}

__device__ __forceinline__ void store_c(
    f32x4 (&acc)[2][8], const unsigned short* __restrict__ bias,
    unsigned short* __restrict__ C, int M, int blockRow, int ldc, int coloff)
{
    int t = threadIdx.x;
    int wave = t >> 6, lane = t & 63, quad = lane >> 4, l16 = lane & 15;
    int rowbase = wave * 32;
    #pragma unroll
    for (int rt = 0; rt < 2; ++rt) {
        #pragma unroll
        for (int ct = 0; ct < 8; ++ct) {
            int col = ct * 16 + l16;
            float bv = bias ? bf2f(bias[col]) : 0.f;
            #pragma unroll
            for (int r = 0; r < 4; ++r) {
                int grow = blockRow + rowbase + rt * 16 + quad * 4 + r;
                if (grow < M) {
                    float v = acc[rt][ct][r] + bv;
                    C[(size_t)grow * ldc + coloff + col] = f2bf(v);
                }
            }
        }
    }
}

// ---------------- weight composition: Wc[b] = win_w[l] @ wrel[b], bc[b] = win_b[l] @ wrel[b] ----------------
__global__ __launch_bounds__(256) void gemm_compose(
    const unsigned short* __restrict__ w_in, const unsigned short* __restrict__ wrel,
    const unsigned short* __restrict__ b_in, unsigned short* __restrict__ wc,
    unsigned short* __restrict__ bc)
{
    __shared__ unsigned short As[DD];
    __shared__ unsigned short Wt[DD];
    f32x4 acc[2][8];
    int b = blockIdx.x;          // l*4 + r
    int l = b >> 2;
    const unsigned short* A = w_in + (size_t)l * DD;
    const unsigned short* W = wrel + (size_t)b * DD;
    gemm_core(A, W, 128, 0, As, Wt, acc);
    store_c(acc, nullptr, wc + (size_t)b * DD, 128, 0, D, 0);
    int t = threadIdx.x;
    if (t < 128) {
        float s = 0.f;
        for (int k = 0; k < 128; ++k)
            s += bf2f(b_in[l * D + k]) * bf2f(W[k * D + t]);
        bc[b * D + t] = f2bf(s);
    }
}

// ---------------- pre-transpose + swizzle 13 weight mats ----------------
__global__ __launch_bounds__(256) void k_prepw(
    const unsigned short* __restrict__ wbase, const unsigned short* __restrict__ wc,
    unsigned short* __restrict__ wtg, int o4, int o7)
{
    int m = blockIdx.x >> 3;
    int sub = blockIdx.x & 7;
    const unsigned short* src;
    if (m == 0)       src = wbase;                         // w_proj
    else if (m <= 2)  src = wbase + o4 + (m - 1) * DD;     // w_in[l]
    else if (m <= 10) src = wc + (size_t)(m - 3) * DD;     // composed wc[l*4+r]
    else              src = wbase + o7 + (m - 11) * DD;    // w_out[l]
    int c = sub * 256 + threadIdx.x;   // 0..2047
    int n = c >> 4;
    int kc = c & 15;
    unsigned short tmp[8];
    #pragma unroll
    for (int ko = 0; ko < 8; ++ko) tmp[ko] = src[(kc * 8 + ko) * 128 + n];
    *((uint4*)(wtg + (size_t)m * DD + n * 128 + ((kc ^ (n & 15)) * 8))) = *(uint4*)tmp;
}

// ---------------- FAST gemm core: W pre-transposed/swizzled, A direct from global ----------------
__device__ __forceinline__ void gemm_core_fast(
    const unsigned short* __restrict__ A,
    const unsigned short* __restrict__ Wt_g,
    int M, int blockRow, unsigned short* Wt, f32x4 (&acc)[2][8])
{
    int t = threadIdx.x;
    #pragma unroll
    for (int i = 0; i < 8; ++i)
        ((uint4*)Wt)[t + i * 256] = ((const uint4*)Wt_g)[t + i * 256];

    int wave = t >> 6, lane = t & 63, quad = lane >> 4, l16 = lane & 15;
    int rowbase = blockRow + wave * 32;
    int r0 = min(rowbase + l16, M - 1);
    int r1 = min(rowbase + 16 + l16, M - 1);
    const unsigned short* a0 = A + (size_t)r0 * D;
    const unsigned short* a1 = A + (size_t)r1 * D;
    short8 af[2][4];
    #pragma unroll
    for (int ks = 0; ks < 4; ++ks) {
        int chunk = ks * 4 + quad;
        af[0][ks] = *((const short8*)(a0 + chunk * 8));
        af[1][ks] = *((const short8*)(a1 + chunk * 8));
    }
    #pragma unroll
    for (int a = 0; a < 2; ++a)
        #pragma unroll
        for (int b = 0; b < 8; ++b) acc[a][b] = (f32x4){0.f, 0.f, 0.f, 0.f};
    __syncthreads();
    #pragma unroll
    for (int ks = 0; ks < 4; ++ks) {
        int chunk = ks * 4 + quad;
        short8 bf[8];
        #pragma unroll
        for (int ct = 0; ct < 8; ++ct)
            bf[ct] = *((const short8*)&Wt[(ct * 16 + l16) * 128 + ((chunk ^ l16) * 8)]);
        #pragma unroll
        for (int rt = 0; rt < 2; ++rt)
            #pragma unroll
            for (int ct = 0; ct < 8; ++ct)
                acc[rt][ct] = __builtin_amdgcn_mfma_f32_16x16x32_bf16(af[rt][ks], bf[ct], acc[rt][ct], 0, 0, 0);
    }
}

// ---------------- plain fast GEMM ----------------
__global__ __launch_bounds__(256) void gemm_fast(
    const unsigned short* __restrict__ A, const unsigned short* __restrict__ Wt_g,
    const unsigned short* __restrict__ bias, unsigned short* __restrict__ C,
    int M, int ldc, int coloff)
{
    __shared__ unsigned short Wt[DD];
    f32x4 acc[2][8];
    gemm_core_fast(A, Wt_g, M, blockIdx.x * 128, Wt, acc);
    store_c(acc, bias, C, M, blockIdx.x * 128, ldc, coloff);
}

// ---------------- proj GEMM + per-block BN partial stats ----------------
__global__ __launch_bounds__(256) void gemm_proj(
    const unsigned short* __restrict__ A, const unsigned short* __restrict__ Wt_g,
    const unsigned short* __restrict__ bias, unsigned short* __restrict__ C,
    int M, float* __restrict__ psum, float* __restrict__ psq)
{
    __shared__ unsigned short Wt[DD];
    __shared__ float smS[4][128], smQ[4][128];
    f32x4 acc[2][8];
    int blockRow = blockIdx.x * 128;
    gemm_core_fast(A, Wt_g, M, blockRow, Wt, acc);

    int t = threadIdx.x;
    int wave = t >> 6, lane = t & 63, quad = lane >> 4, l16 = lane & 15;
    int rowbase = wave * 32;
    #pragma unroll
    for (int ct = 0; ct < 8; ++ct) {
        int col = ct * 16 + l16;
        float bv = bf2f(bias[col]);
        float ps = 0.f, pq = 0.f;
        #pragma unroll
        for (int rt = 0; rt < 2; ++rt) {
            #pragma unroll
            for (int r = 0; r < 4; ++r) {
                int grow = blockRow + rowbase + rt * 16 + quad * 4 + r;
                if (grow < M) {
                    float v = acc[rt][ct][r] + bv;
                    C[(size_t)grow * D + col] = f2bf(v);
                    ps += v; pq += v * v;
                }
            }
        }
        ps += __shfl_xor(ps, 16, 64); ps += __shfl_xor(ps, 32, 64);
        pq += __shfl_xor(pq, 16, 64); pq += __shfl_xor(pq, 32, 64);
        if (quad == 0) { smS[wave][col] = ps; smQ[wave][col] = pq; }
    }
    __syncthreads();
    if (t < 128) {
        float s = smS[0][t] + smS[1][t] + smS[2][t] + smS[3][t];
        float q = smQ[0][t] + smQ[1][t] + smQ[2][t] + smQ[3][t];
        psum[blockIdx.x * 128 + t] = s;
        psq[blockIdx.x * 128 + t] = q;
    }
}

// ---------------- fused per-layer GEMM: slice 0 -> xl (pre-scaled by dinv); 1..4 -> y_r ----------------
__global__ __launch_bounds__(256) void gemm_fused(
    const unsigned short* __restrict__ h, const unsigned short* __restrict__ wtg,
    const unsigned short* __restrict__ b_in_l, const unsigned short* __restrict__ bc_l,
    unsigned short* __restrict__ xl, unsigned short* __restrict__ y,
    const float* __restrict__ dinv, int M, int l)
{
    __shared__ unsigned short Wt[DD];
    f32x4 acc[2][8];
    int slice = blockIdx.y;
    int m = (slice == 0) ? (1 + l) : (3 + l * 4 + slice - 1);
    int blockRow = blockIdx.x * 128;
    gemm_core_fast(h, wtg + (size_t)m * DD, M, blockRow, Wt, acc);
    int t = threadIdx.x;
    int wave = t >> 6, lane = t & 63, quad = lane >> 4, l16 = lane & 15;
    int rowbase = wave * 32;
    if (slice == 0) {
        const unsigned short* bias = b_in_l;
        #pragma unroll
        for (int rt = 0; rt < 2; ++rt) {
            float dv[4];
            #pragma unroll
            for (int r = 0; r < 4; ++r) {
                int grow = min(blockRow + rowbase + rt * 16 + quad * 4 + r, M - 1);
                dv[r] = dinv[grow];
            }
            #pragma unroll
            for (int ct = 0; ct < 8; ++ct) {
                int col = ct * 16 + l16;
                float bv = bf2f(bias[col]);
                #pragma unroll
                for (int r = 0; r < 4; ++r) {
                    int grow = blockRow + rowbase + rt * 16 + quad * 4 + r;
                    if (grow < M)
                        xl[(size_t)grow * D + col] = f2bf((acc[rt][ct][r] + bv) * dv[r]);
                }
            }
        }
    } else {
        store_c(acc, bc_l + (slice - 1) * D, y, M, blockRow, 4 * D, (slice - 1) * D);
    }
}

// ---------------- final GEMM on compact zg rows + exact GeLU epilogue ----------------
__global__ __launch_bounds__(256) void gemm_out(
    const unsigned short* __restrict__ zg, const unsigned short* __restrict__ Wt_g,
    const unsigned short* __restrict__ bias, void* __restrict__ out,
    int M, const unsigned short* __restrict__ xprobe)
{
    int fl = vote_flag(xprobe);
    __shared__ unsigned short Wt[DD];
    f32x4 acc[2][8];
    int blockRow = blockIdx.x * 128;
    gemm_core_fast(zg, Wt_g, M, blockRow, Wt, acc);
    int t = threadIdx.x;
    int wave = t >> 6, lane = t & 63, quad = lane >> 4, l16 = lane & 15;
    int rowbase = wave * 32;
    #pragma unroll
    for (int rt = 0; rt < 2; ++rt) {
        #pragma unroll
        for (int ct = 0; ct < 8; ++ct) {
            int col = ct * 16 + l16;
            float bv = bf2f(bias[col]);
            #pragma unroll
            for (int r = 0; r < 4; ++r) {
                int grow = blockRow + rowbase + rt * 16 + quad * 4 + r;
                if (grow < M) {
                    float v = acc[rt][ct][r] + bv;
                    float gl = 0.5f * v * (1.f + erff(v * 0.70710678118654752f));
                    size_t o = (size_t)grow * D + col;
                    if (fl) ((float*)out)[o] = gl;
                    else    ((unsigned short*)out)[o] = f2bf(gl);
                }
            }
        }
    }
}

// ================= atomic-free CSR build via single-digit bucket sort =================
__global__ __launch_bounds__(256) void k_hista(
    const int* __restrict__ ei, int E,
    unsigned int* __restrict__ part_dst, unsigned int* __restrict__ part_src)
{
    __shared__ unsigned int hd[256], hs[256];
    int b = blockIdx.x, t = threadIdx.x;
    hd[t] = 0u; hs[t] = 0u;
    __syncthreads();
    int base = b * 2048;
    #pragma unroll
    for (int i = 0; i < 8; ++i) {
        int e = base + t + i * 256;
        if (e < E) {
            atomicAdd(&hd[((unsigned int)ei[e]) >> 8], 1u);
            atomicAdd(&hs[((unsigned int)ei[E + e]) >> 8], 1u);
        }
    }
    __syncthreads();
    part_dst[b * 256 + t] = hd[t];
    part_src[b * 256 + t] = hs[t];
}

__global__ void k_scanpart(unsigned int* __restrict__ part_d, unsigned int* __restrict__ part_s,
                           unsigned int* __restrict__ btot_d, unsigned int* __restrict__ btot_s,
                           int BA)
{
    __shared__ unsigned int arr[512];
    unsigned int* part = blockIdx.y ? part_s : part_d;
    unsigned int* btot = blockIdx.y ? btot_s : btot_d;
    int bucket = blockIdx.x, t = threadIdx.x;
    unsigned int v0 = (t < BA) ? part[t * 256 + bucket] : 0u;
    unsigned int v1 = (t + 256 < BA) ? part[(t + 256) * 256 + bucket] : 0u;
    arr[t] = v0; arr[t + 256] = v1;
    __syncthreads();
    for (int off = 1; off < 512; off <<= 1) {
        unsigned int a = arr[t], b2 = arr[t + 256];
        unsigned int pa = (t >= off) ? arr[t - off] : 0u;
        unsigned int pb = (t + 256 >= off) ? arr[t + 256 - off] : 0u;
        __syncthreads();
        arr[t] = a + pa; arr[t + 256] = b2 + pb;
        __syncthreads();
    }
    if (t < BA) part[t * 256 + bucket] = arr[t] - v0;
    if (t + 256 < BA) part[(t + 256) * 256 + bucket] = arr[t + 256] - v1;
    if (t == 0) btot[bucket] = arr[511];
}

__global__ void k_scanbase(const unsigned int* __restrict__ btot_d, const unsigned int* __restrict__ btot_s,
                           unsigned int* __restrict__ bbase_d, unsigned int* __restrict__ bbase_s)
{
    __shared__ unsigned int a1[256], a2[256];
    int t = threadIdx.x;
    unsigned int vd = btot_d[t], vs = btot_s[t];
    a1[t] = vd; a2[t] = vs;
    __syncthreads();
    for (int off = 1; off < 256; off <<= 1) {
        unsigned int x = a1[t], y = a2[t];
        unsigned int px = (t >= off) ? a1[t - off] : 0u;
        unsigned int py = (t >= off) ? a2[t - off] : 0u;
        __syncthreads();
        a1[t] = x + px; a2[t] = y + py;
        __syncthreads();
    }
    bbase_d[t] = a1[t] - vd;
    bbase_s[t] = a2[t] - vs;
    if (t == 255) { bbase_d[256] = a1[255]; bbase_s[256] = a2[255]; }
}

__global__ __launch_bounds__(256) void k_bscatter(
    const int* __restrict__ ei, const int* __restrict__ et, int E,
    const unsigned int* __restrict__ part_dst, const unsigned int* __restrict__ part_src,
    const unsigned int* __restrict__ bbase_d, const unsigned int* __restrict__ bbase_s,
    uint2* __restrict__ ebuck, unsigned short* __restrict__ sbuck)
{
    __shared__ unsigned int cd[256], cs[256];
    int b = blockIdx.x, t = threadIdx.x;
    cd[t] = part_dst[b * 256 + t] + bbase_d[t];
    cs[t] = part_src[b * 256 + t] + bbase_s[t];
    __syncthreads();
    int base = b * 2048;
    #pragma unroll
    for (int i = 0; i < 8; ++i) {
        int e = base + t + i * 256;
        if (e < E) {
            unsigned int d = (unsigned int)ei[e];
            unsigned int s = (unsigned int)ei[E + e];
            unsigned int tt = (unsigned int)et[e];
            unsigned int pd = atomicAdd(&cd[d >> 8], 1u);
            ebuck[pd] = make_uint2(d, s | (tt << 16));
            unsigned int ps = atomicAdd(&cs[s >> 8], 1u);
            sbuck[ps] = (unsigned short)s;
        }
    }
}

// y=0: per-dst-bucket counting sort -> rp + pckd; y=1: per-src-bucket histogram -> dinv
__global__ __launch_bounds__(256) void k_buckets(
    const unsigned int* __restrict__ bbase_d, const uint2* __restrict__ ebuck,
    unsigned int* __restrict__ rp, unsigned int* __restrict__ pckd,
    const unsigned int* __restrict__ bbase_s, const unsigned short* __restrict__ sbuck,
    float* __restrict__ dinv, int N)
{
    __shared__ uint2 ebuf[BCAP];
    __shared__ unsigned int bins[256], scn[256], cur[256];
    int b = blockIdx.x, t = threadIdx.x;
    if (blockIdx.y == 0) {
        unsigned int beg = bbase_d[b], end = bbase_d[b + 1];
        unsigned int cnt = end - beg;
        bins[t] = 0u;
        __syncthreads();
        bool fit = cnt <= (unsigned int)BCAP;
        if (fit) {
            for (unsigned int i = t; i < cnt; i += 256) {
                uint2 v = ebuck[beg + i];
                ebuf[i] = v;
                atomicAdd(&bins[v.x & 255u], 1u);
            }
        } else {
            for (unsigned int i = t; i < cnt; i += 256)
                atomicAdd(&bins[ebuck[beg + i].x & 255u], 1u);
        }
        __syncthreads();
        scn[t] = bins[t];
        __syncthreads();
        for (int off = 1; off < 256; off <<= 1) {
            unsigned int v = scn[t];
            unsigned int a = (t >= off) ? scn[t - off] : 0u;
            __syncthreads();
            scn[t] = v + a;
            __syncthreads();
        }
        unsigned int ex = scn[t] - bins[t];
        int n = (b << 8) + t;
        if (n <= N) rp[n] = beg + ex;
        cur[t] = beg + ex;
        __syncthreads();
        if (fit) {
            for (unsigned int i = t; i < cnt; i += 256) {
                uint2 v = ebuf[i];
                unsigned int pos = atomicAdd(&cur[v.x & 255u], 1u);
                pckd[pos] = v.y;
            }
        } else {
            for (unsigned int i = t; i < cnt; i += 256) {
                uint2 v = ebuck[beg + i];
                unsigned int pos = atomicAdd(&cur[v.x & 255u], 1u);
                pckd[pos] = v.y;
            }
        }
    } else {
        unsigned int beg = bbase_s[b], end = bbase_s[b + 1];
        bins[t] = 0u;
        __syncthreads();
        for (unsigned int i = beg + t; i < end; i += 256)
            atomicAdd(&bins[sbuck[i] & 255u], 1u);
        __syncthreads();
        int n = (b << 8) + t;
        if (n < N) {
            unsigned int dg = bins[t];
            dinv[n] = dg ? rsqrtf((float)dg) : 0.f;
        }
    }
}

// ---------------- BN stats reduce (1 block) ----------------
__global__ void k_bnstats(const float* __restrict__ psum, const float* __restrict__ psq,
                          int nb, int N, const unsigned short* __restrict__ g,
                          const unsigned short* __restrict__ b,
                          float* __restrict__ scale, float* __restrict__ shift) {
    int col = threadIdx.x & 127, h = threadIdx.x >> 7;
    float s = 0.f, q = 0.f;
    for (int i = h; i < nb; i += 2) { s += psum[i * 128 + col]; q += psq[i * 128 + col]; }
    __shared__ float sS[256], sQ[256];
    sS[threadIdx.x] = s; sQ[threadIdx.x] = q;
    __syncthreads();
    if (h == 0) {
        s = sS[col] + sS[col + 128];
        q = sQ[col] + sQ[col + 128];
        float inv = 1.f / (float)N;
        float mean = s * inv;
        float var = fmaxf(q * inv - mean * mean, 0.f);
        float sc = rsqrtf(var + 1e-5f) * bf2f(g[col]);
        scale[col] = sc;
        shift[col] = bf2f(b[col]) - mean * sc;
    }
}

// ---------------- BN apply + relu (vec 8 shorts/thread) ----------------
__global__ void k_bnrelu(unsigned short* __restrict__ h, const float* __restrict__ scale,
                         const float* __restrict__ shift, int n8) {
    int i = blockIdx.x * blockDim.x + threadIdx.x;
    if (i >= n8) return;
    int cb = (i & 15) * 8;
    uint4 v = ((uint4*)h)[i];
    unsigned int* w = (unsigned int*)&v;
    #pragma unroll
    for (int j = 0; j < 4; ++j) {
        int c = cb + j * 2;
        float v0 = __uint_as_float(w[j] << 16);
        float v1 = __uint_as_float(w[j] & 0xFFFF0000u);
        v0 = fmaxf(fmaf(v0, scale[c], shift[c]), 0.f);
        v1 = fmaxf(fmaf(v1, scale[c + 1], shift[c + 1]), 0.f);
        w[j] = (unsigned int)f2bf(v0) | ((unsigned int)f2bf(v1) << 16);
    }
    ((uint4*)h)[i] = v;
}

// ---------------- edge aggregation: 1 wave/node, 8 edges in flight (2x4 unroll), 8 ch/lane ----------------
__device__ __forceinline__ void acc_edge(uint4 xv, uint4 yv, float vm,
                                         float* g, float* dd, float* ss) {
    const unsigned int* xw = (const unsigned int*)&xv;
    const unsigned int* yw = (const unsigned int*)&yv;
    #pragma unroll
    for (int w = 0; w < 4; ++w) {
        float x0 = __uint_as_float(xw[w] << 16);
        float x1 = __uint_as_float(xw[w] & 0xFFFF0000u);
        float v0 = __uint_as_float(yw[w] << 16);
        float v1 = __uint_as_float(yw[w] & 0xFFFF0000u);
        int j0 = 2 * w, j1 = 2 * w + 1;
        g[j0] = fmaf(x0, vm, g[j0]);
        g[j1] = fmaf(x1, vm, g[j1]);
        float e0 = __expf(v0), e1 = __expf(v1);
        dd[j0] = fmaf(e0, vm, dd[j0]);
        dd[j1] = fmaf(e1, vm, dd[j1]);
        ss[j0] = fmaf(v0 * e0, vm, ss[j0]);
        ss[j1] = fmaf(v1 * e1, vm, ss[j1]);
    }
}

__global__ __launch_bounds__(256) void k_edge(
    const unsigned int* __restrict__ rp, const unsigned int* __restrict__ packed,
    const unsigned short* __restrict__ xl, const unsigned short* __restrict__ y,
    const float* __restrict__ dinv, unsigned short* __restrict__ zout,
    int NN, int RD, const int* __restrict__ nodes)
{
    int lane = threadIdx.x & 63;
    int slot = blockIdx.x * 4 + (threadIdx.x >> 6);
    if (slot >= NN) return;
    int node = nodes ? nodes[slot] : slot;
    node = __builtin_amdgcn_readfirstlane(node);
    unsigned int beg = rp[node], end = rp[node + 1];
    int eg = lane >> 4;
    int cb = (lane & 15) * 8;
    float g[8], dd[8], ss[8];
    #pragma unroll
    for (int j = 0; j < 8; ++j) { g[j] = 0.f; dd[j] = 0.f; ss[j] = 0.f; }

    for (unsigned int e0 = beg; e0 < end; e0 += 8) {
        unsigned int eA = e0 + (unsigned int)eg;
        unsigned int eB = eA + 4u;
        float vmA = (eA < end) ? 1.f : 0.f;
        float vmB = (eB < end) ? 1.f : 0.f;
        unsigned int pA = packed[(eA < end) ? eA : beg];
        unsigned int pB = packed[(eB < end) ? eB : beg];
        unsigned int sA = pA & 0xFFFFu, tA = pA >> 16;
        unsigned int sB = pB & 0xFFFFu, tB = pB >> 16;
        uint4 xvA = *((const uint4*)(xl + (size_t)sA * D + cb));
        uint4 yvA = *((const uint4*)(y + (size_t)sA * RD + tA * D + cb));
        uint4 xvB = *((const uint4*)(xl + (size_t)sB * D + cb));
        uint4 yvB = *((const uint4*)(y + (size_t)sB * RD + tB * D + cb));
        acc_edge(xvA, yvA, vmA, g, dd, ss);
        acc_edge(xvB, yvB, vmB, g, dd, ss);
    }

    #pragma unroll
    for (int j = 0; j < 8; ++j) {
        g[j]  += __shfl_xor(g[j], 16, 64);  g[j]  += __shfl_xor(g[j], 32, 64);
        dd[j] += __shfl_xor(dd[j], 16, 64); dd[j] += __shfl_xor(dd[j], 32, 64);
        ss[j] += __shfl_xor(ss[j], 16, 64); ss[j] += __shfl_xor(ss[j], 32, 64);
    }
    if (eg == 0) {
        float dn = dinv[node];
        unsigned int o[4];
        #pragma unroll
        for (int w = 0; w < 4; ++w) {
            int j0 = w * 2, j1 = w * 2 + 1;
            float m0 = (dd[j0] > 0.f) ? ss[j0] / dd[j0] : 0.f;
            float m1 = (dd[j1] > 0.f) ? ss[j1] / dd[j1] : 0.f;
            float z0 = fmaf(g[j0], dn, 0.1f * fmaxf(m0, 0.f));
            float z1 = fmaf(g[j1], dn, 0.1f * fmaxf(m1, 0.f));
            o[w] = (unsigned int)f2bf(z0) | ((unsigned int)f2bf(z1) << 16);
        }
        *((uint4*)(zout + (size_t)slot * D + cb)) = *(uint4*)o;
    }
}

extern "C" void kernel_launch(void* const* d_in, const int* in_sizes, int n_in,
                              void* d_out, int out_size, void* d_ws, size_t ws_size,
                              hipStream_t stream)
{
    const int* ei  = (const int*)d_in[1];
    const int* idx = (const int*)d_in[2];
    const int* et  = (const int*)d_in[3];
    const unsigned short* xprobe = (const unsigned short*)d_in[0];

    int N  = in_sizes[0] / D;            // 48758
    int E  = in_sizes[1] / 2;            // 780000
    int NI = in_sizes[2];                // 10000
    int L  = in_sizes[9] / (D * D);      // 2
    int R  = in_sizes[11] / (L * D * D); // 4
    int RD = R * D;

    int NB = (N + 255) >> 8;             // dst/src buckets
    int BA = (E + 2047) / 2048;          // histogram/scatter blocks

    char* ws = (char*)d_ws;
    size_t off = 0;
    auto alloc = [&](size_t bytes) -> char* {
        char* p = ws + off;
        off += (bytes + 255) & ~(size_t)255;
        return p;
    };
    unsigned short* h    = (unsigned short*)alloc((size_t)N * D * 2);
    unsigned short* xl   = (unsigned short*)alloc((size_t)N * D * 2);
    unsigned short* y    = (unsigned short*)alloc((size_t)N * RD * 2);
    unsigned short* z    = (unsigned short*)alloc((size_t)N * D * 2);
    unsigned short* xb   = (unsigned short*)alloc((size_t)N * D * 2);
    unsigned short* zg   = (unsigned short*)alloc((size_t)NI * D * 2);
    float*          dinv = (float*)alloc((size_t)N * 4);
    unsigned int*   rp   = (unsigned int*)alloc((size_t)(N + 1) * 4);
    unsigned int*   pckd = (unsigned int*)alloc((size_t)E * 4);
    int gb  = (N + 127) / 128;
    float*          psum = (float*)alloc((size_t)gb * 128 * 4);
    float*          psq  = (float*)alloc((size_t)gb * 128 * 4);
    float*          bscale = (float*)alloc(128 * 4);
    float*          bshift = (float*)alloc(128 * 4);
    // bucket-sort scratch
    unsigned int*   part_dst = (unsigned int*)alloc((size_t)BA * 256 * 4);
    unsigned int*   part_src = (unsigned int*)alloc((size_t)BA * 256 * 4);
    unsigned int*   btot_d   = (unsigned int*)alloc(256 * 4);
    unsigned int*   btot_s   = (unsigned int*)alloc(256 * 4);
    unsigned int*   bbase_d  = (unsigned int*)alloc(257 * 4);
    unsigned int*   bbase_s  = (unsigned int*)alloc(257 * 4);
    // aliases into regions dead during graph prep
    uint2*          ebuck = (uint2*)y;           // E*8 <= N*RD*2
    unsigned short* sbuck = (unsigned short*)z;  // E*2 <= N*D*2
    // contiguous bf16 weight region
    int o1 = D * D;                // w_proj
    int o2 = o1 + D;               // b_proj
    int o3 = o2 + D;               // bn_g
    int o4 = o3 + D;               // bn_b
    int o5 = o4 + L * D * D;       // w_in
    int o6 = o5 + L * D;           // b_in
    int o7 = o6 + L * R * D * D;   // w_rel
    int o8 = o7 + L * D * D;       // w_out
    int wt = o8 + L * D;           // b_out end
    unsigned short* wbase  = (unsigned short*)alloc((size_t)wt * 2);
    unsigned short* b_proj = wbase + o1;
    unsigned short* g_bn   = wbase + o2;
    unsigned short* b_bn   = wbase + o3;
    unsigned short* w_in   = wbase + o4;
    unsigned short* b_in   = wbase + o5;
    unsigned short* w_rel  = wbase + o6;
    unsigned short* b_out  = wbase + o8;
    unsigned short* wc     = (unsigned short*)alloc((size_t)L * R * D * D * 2);
    unsigned short* bc     = (unsigned short*)alloc((size_t)L * R * D * 2);
    unsigned short* wtg    = (unsigned short*)alloc((size_t)13 * DD * 2);
    (void)ws_size; (void)n_in; (void)out_size;

    int gb2 = (NI + 127) / 128;
    int nb4 = (N + 3) / 4;
    int ni4 = (NI + 3) / 4;

    // input normalization (dtype vote inline)
    int n4 = N * D / 4;
    int nbx = (n4 + 255) / 256;
    int nbw = (wt + 255) / 256;
    k_normall<<<nbx + nbw, 256, 0, stream>>>(
        d_in[0], xb, n4, nbx,
        d_in[5], d_in[6], d_in[7], d_in[8], d_in[9], d_in[10], d_in[11], d_in[12], d_in[13],
        o1, o2, o3, o4, o5, o6, o7, o8, wt, wbase);

    // atomic-free CSR build
    k_hista<<<BA, 256, 0, stream>>>(ei, E, part_dst, part_src);
    k_scanpart<<<dim3(256, 2), 256, 0, stream>>>(part_dst, part_src, btot_d, btot_s, BA);
    k_scanbase<<<1, 256, 0, stream>>>(btot_d, btot_s, bbase_d, bbase_s);
    k_bscatter<<<BA, 256, 0, stream>>>(ei, et, E, part_dst, part_src, bbase_d, bbase_s, ebuck, sbuck);
    k_buckets<<<dim3(NB, 2), 256, 0, stream>>>(bbase_d, ebuck, rp, pckd, bbase_s, sbuck, dinv, N);

    // composed weights, then pre-transposed/swizzled GEMM weights
    gemm_compose<<<L * R, 256, 0, stream>>>(w_in, w_rel, b_in, wc, bc);
    k_prepw<<<13 * 8, 256, 0, stream>>>(wbase, wc, wtg, o4, o7);

    // proj + BN + relu
    gemm_proj<<<gb, 256, 0, stream>>>(xb, wtg, b_proj, h, N, psum, psq);
    k_bnstats<<<1, 256, 0, stream>>>(psum, psq, gb, N, g_bn, b_bn, bscale, bshift);
    int n8 = N * D / 8;
    k_bnrelu<<<(n8 + 255) / 256, 256, 0, stream>>>(h, bscale, bshift, n8);

    // layer 0 (full graph)
    gemm_fused<<<dim3(gb, 1 + R), 256, 0, stream>>>(h, wtg, b_in, bc, xl, y, dinv, N, 0);
    k_edge<<<nb4, 256, 0, stream>>>(rp, pckd, xl, y, dinv, z, N, RD, nullptr);
    gemm_fast<<<gb, 256, 0, stream>>>(z, wtg + (size_t)11 * DD, b_out, h, N, D, 0);

    // layer 1 (aggregate only idx rows, compact output)
    gemm_fused<<<dim3(gb, 1 + R), 256, 0, stream>>>(h, wtg, b_in + D, bc + R * D, xl, y, dinv, N, 1);
    k_edge<<<ni4, 256, 0, stream>>>(rp, pckd, xl, y, dinv, zg, NI, RD, idx);

    // final GEMM on compact rows + GeLU
    gemm_out<<<gb2, 256, 0, stream>>>(zg, wtg + (size_t)12 * DD, b_out + D, d_out, NI, xprobe);
}